// Round 8
// baseline (180.823 us; speedup 1.0000x reference)
//
#include <hip/hip_runtime.h>

// GQA attention fused pipeline for MI355X (gfx950).
// cvt(fused) -> GEMM(QKV, global_load_lds staging) -> RoPE/scatter (K
// fragment-major) + V-transpose (fragment-major) -> flash attention (swapped
// 32x32 MFMA, split-K x4, static-max softmax, K/V software-pipelined)
// -> GEMM(out, global_load_lds staging).

typedef __bf16 bf16x8 __attribute__((ext_vector_type(8)));
typedef float f32x4 __attribute__((ext_vector_type(4)));
typedef float f32x16 __attribute__((ext_vector_type(16)));
typedef int i32x4 __attribute__((ext_vector_type(4)));
typedef unsigned short ushort4v __attribute__((ext_vector_type(4)));
typedef unsigned short ushort8v __attribute__((ext_vector_type(8)));
typedef unsigned short u16;
typedef unsigned int u32;

#define DEVINL __device__ __forceinline__

DEVINL float bf2f(u16 u) {
  unsigned int x = ((unsigned int)u) << 16;
  return __builtin_bit_cast(float, x);
}
DEVINL u16 f2bf(float f) {  // RTNE
  unsigned int x = __builtin_bit_cast(unsigned int, f);
  x += 0x7fffu + ((x >> 16) & 1u);
  return (u16)(x >> 16);
}
// raw 2^x — single v_exp_f32, skips OCML range-guard sequence
DEVINL float exp2r(float x) {
  float r;
  asm("v_exp_f32 %0, %1" : "=v"(r) : "v"(x));
  return r;
}
// async global->LDS, 16B per lane; LDS dest = wave-uniform base + lane*16
DEVINL void gld16(const u16* g, u16* l) {
  __builtin_amdgcn_global_load_lds(
      (const __attribute__((address_space(1))) void*)g,
      (__attribute__((address_space(3))) void*)l, 16, 0, 0);
}

constexpr int Bb = 2, Tt = 2048, Dd = 1024, QH = 16, KVH = 4, HD = 64;
// fold softmax scale (1/sqrt(64)) and log2(e) into Q so we can use exp2
constexpr float SCALE_L2E = 0.125f * 1.44269504088896340736f;
// per-(b,kvh) fragment-major K/V extent: 2048 keys * 64 dims
constexpr int KVSZ = 131072;

// ---------------------------------------------------------------- fused convert
__global__ void cvt_all(const float* __restrict__ x, const float* __restrict__ Wq,
                        const float* __restrict__ Wkv, const float* __restrict__ Wo,
                        u16* __restrict__ xb, u16* __restrict__ wqkv,
                        u16* __restrict__ wob) {
  int i = blockIdx.x * 256 + threadIdx.x;  // grid covers 1,703,936 float4s exactly
  const float* src;
  u16* dst;
  if (i < 1048576) {
    src = x; dst = xb;
  } else if (i < 1310720) {
    src = Wq - (size_t)1048576 * 4; dst = wqkv - (size_t)1048576 * 4;
  } else if (i < 1441792) {
    src = Wkv - (size_t)1310720 * 4; dst = wqkv + (size_t)1024 * 1024 - (size_t)1310720 * 4;
  } else {
    src = Wo - (size_t)1441792 * 4; dst = wob - (size_t)1441792 * 4;
  }
  float4 v = reinterpret_cast<const float4*>(src)[i];
  ushort4v o = {f2bf(v.x), f2bf(v.y), f2bf(v.z), f2bf(v.w)};
  *reinterpret_cast<ushort4v*>(dst + (size_t)i * 4) = o;
}

// ---------------------------------------------------------------- GEMM C = A(M,K) @ B(N,K)^T
// m97 2-phase structure: global_load_lds width-16 staging (linear LDS), then
// ds_read_b128 fragment reads + 16x16x32 MFMA. 128x128 tile, BK=64, 4 waves.
template <bool OUT_F32>
__global__ __launch_bounds__(256) void gemm_bt(const u16* __restrict__ A,
                                               const u16* __restrict__ Bw,
                                               void* __restrict__ Cout, int M, int N, int K) {
  __shared__ alignas(16) u16 lA[128 * 64];
  __shared__ alignas(16) u16 lB[128 * 64];
  const int tid = threadIdx.x;
  const int w = tid >> 6, lane = tid & 63;
  const int r16 = lane & 15, g4 = lane >> 4;
  const int row0 = blockIdx.y * 128, col0 = blockIdx.x * 128;
  const int sr = tid >> 3, sc = tid & 7;  // lane l of wave w: sr=w*8+(l>>3), sc=l&7
  const int NT = K >> 6;
  const int wm = (w >> 1) * 64, wn = (w & 1) * 64;

  f32x4 acc[4][4];
#pragma unroll
  for (int i = 0; i < 4; ++i)
#pragma unroll
    for (int j = 0; j < 4; ++j) acc[i][j] = f32x4{0.f, 0.f, 0.f, 0.f};

  // per-lane global source cursors; wave-uniform LDS bases (dest = base + lane*16B)
  const u16* Ap = A + (size_t)(row0 + sr) * K + sc * 8;
  const u16* Bp = Bw + (size_t)(col0 + sr) * K + sc * 8;
  u16* lAb = &lA[(size_t)(w * 8) * 64];
  u16* lBb = &lB[(size_t)(w * 8) * 64];

  for (int kt = 0; kt < NT; ++kt) {
    __syncthreads();  // all waves done reading LDS from previous step
    const int k0 = kt << 6;
#pragma unroll
    for (int i = 0; i < 4; ++i) {
      gld16(Ap + (size_t)(i * 32) * K + k0, lAb + i * 32 * 64);
      gld16(Bp + (size_t)(i * 32) * K + k0, lBb + i * 32 * 64);
    }
    __syncthreads();  // compiler drains vmcnt(0) before barrier -> LDS ready
#pragma unroll
    for (int kk = 0; kk < 2; ++kk) {
      bf16x8 af[4], bfr[4];
#pragma unroll
      for (int mf = 0; mf < 4; ++mf)
        af[mf] = *reinterpret_cast<const bf16x8*>(
            &lA[(wm + mf * 16 + r16) * 64 + (kk * 4 + g4) * 8]);
#pragma unroll
      for (int nf = 0; nf < 4; ++nf)
        bfr[nf] = *reinterpret_cast<const bf16x8*>(
            &lB[(wn + nf * 16 + r16) * 64 + (kk * 4 + g4) * 8]);
#pragma unroll
      for (int mf = 0; mf < 4; ++mf)
#pragma unroll
        for (int nf = 0; nf < 4; ++nf)
          acc[mf][nf] =
              __builtin_amdgcn_mfma_f32_16x16x32_bf16(af[mf], bfr[nf], acc[mf][nf], 0, 0, 0);
    }
  }

#pragma unroll
  for (int mf = 0; mf < 4; ++mf)
#pragma unroll
    for (int nf = 0; nf < 4; ++nf)
#pragma unroll
      for (int r = 0; r < 4; ++r) {
        size_t row = (size_t)(row0 + wm + mf * 16 + g4 * 4 + r);
        size_t col = (size_t)(col0 + wn + nf * 16 + r16);
        float v = acc[mf][nf][r];
        if (OUT_F32)
          reinterpret_cast<float*>(Cout)[row * N + col] = v;
        else
          reinterpret_cast<u16*>(Cout)[row * N + col] = f2bf(v);
      }
}

// ---------------------------------------------------------------- RoPE + scatter
// Q row-major. K written FRAGMENT-MAJOR:
//   elem K[bh][t][d] -> bh*KVSZ + ((t>>5)*4 + (d>>4))*512
//                       + (((d>>3)&1)*32 + (t&31))*8 + (d&7)
__global__ void rope_scatter(const u16* __restrict__ P, const float* __restrict__ cosT,
                             const float* __restrict__ sinT, u16* __restrict__ Q,
                             u16* __restrict__ Kc) {
  int idx = blockIdx.x * 256 + threadIdx.x;
  if (idx >= (Bb * Tt) * 640) return;
  int row = idx / 640, p = idx - row * 640;
  int b = row >> 11, t = row & 2047;
  int n, d;
  u16* outp;
  float scl;
  if (p < 512) {
    n = p * 2;
    int h = n >> 6;
    d = n & 63;
    outp = Q + ((size_t)(b * QH + h) * Tt + t) * HD + d;
    scl = SCALE_L2E;
  } else {
    int r2 = p - 512;
    int kvh = r2 >> 5, dp = r2 & 31;
    d = dp * 2;
    n = 1024 + kvh * 128 + d;
    int bh = b * KVH + kvh;
    int kf = d >> 4, h8 = (d >> 3) & 1, j = d & 7;  // j even
    outp = Kc + (size_t)bh * KVSZ + ((t >> 5) * 4 + kf) * 512 + (h8 * 32 + (t & 31)) * 8 + j;
    scl = 1.0f;
  }
  unsigned int pv = *reinterpret_cast<const unsigned int*>(P + (size_t)row * 1536 + n);
  float v0 = bf2f((u16)(pv & 0xffffu)), v1 = bf2f((u16)(pv >> 16));
  float c = cosT[t * HD + d], s = sinT[t * HD + d];
  float o0 = (v0 * c - v1 * s) * scl;
  float o1 = (v1 * c + v0 * s) * scl;
  unsigned int ob = (unsigned int)f2bf(o0) | ((unsigned int)f2bf(o1) << 16);
  *reinterpret_cast<unsigned int*>(outp) = ob;
}

// ---------------------------------------------------------------- V transpose -> fragment-major
__global__ void v_transpose(const u16* __restrict__ P, u16* __restrict__ Vf) {
  __shared__ u16 tile[64][72];
  int bh = blockIdx.y;
  int b = bh >> 2, kvh = bh & 3;
  int t0 = blockIdx.x * 64;
  int tid = threadIdx.x;
  int colbase = 1024 + kvh * 128 + 64;
#pragma unroll
  for (int j = 0; j < 4; ++j) {
    int rr = j * 16 + (tid >> 4);
    int cc = (tid & 15) * 4;
    *reinterpret_cast<uint2*>(&tile[rr][cc]) =
        *reinterpret_cast<const uint2*>(P + (size_t)(b * Tt + t0 + rr) * 1536 + colbase + cc);
  }
  __syncthreads();
#pragma unroll
  for (int kk = 0; kk < 2; ++kk) {
    int CH = kk * 256 + tid;            // 512 chunks of 16B
    int df = CH >> 8, sbks = (CH >> 6) & 3, h8 = (CH >> 5) & 1, l = CH & 31;
    int d = df * 32 + l;
    int c = (sbks >> 1) * 4 + (sbks & 1) * 2 + h8;  // s-chunk within the 64-key tile
    ushort8v v;
#pragma unroll
    for (int j = 0; j < 8; ++j) v[j] = tile[c * 8 + j][d];
    u16* dst = Vf + (size_t)bh * KVSZ + (((t0 >> 6) * 2 + df) * 4 + sbks) * 512 +
               (h8 * 32 + l) * 8;
    *reinterpret_cast<ushort8v*>(dst) = v;
  }
}

// ---------------------------------------------------------------- flash attention v8
// As v7 (8 waves = {spl 0..3}x{qsub 0..1}, static-max softmax, permlane pack,
// pure-sum merge) + software-pipelined loads: K(tile 0) preloaded; per tile,
// V(cur) and K(next) are issued right after the QK MFMAs consume the K regs,
// so both loads hide under softmax+pack+PV instead of stalling the chain.
__global__ __launch_bounds__(512, 4) void attn_fwd8(const u16* __restrict__ Q,
                                                    const u16* __restrict__ Kf,
                                                    const u16* __restrict__ Vf,
                                                    u16* __restrict__ Oa) {
  __shared__ alignas(16) float cmb[2][32][66];  // publish slot: O^T(64) + l
  __shared__ alignas(16) u16 ot[2][32][72];     // final bf16 O, pre-store transpose
  const int tid = threadIdx.x;
  const int w = tid >> 6, lane = tid & 63;
  const int qsub = w & 1, spl = w >> 1;
  const int l31 = lane & 31, hi = lane >> 5;

  const int fid = blockIdx.x;
  const int xcd = fid & 7, idx = fid >> 3;     // xcd == (b,kvh): K/V L2-resident
  const int b = xcd >> 2, kvh = xcd & 3;
  const int g = idx & 3, qblk = idx >> 2;
  const int h = kvh * 4 + g;
  const int t0 = qblk * 64 + qsub * 32;

  const u16* Qh = Q + ((size_t)(b * QH + h) * Tt + t0 + l31) * HD + hi * 8;
  // per-wave K/V cursors advance 4096 elements per 64-key tile
  const u16* Kp = Kf + (size_t)(b * KVH + kvh) * KVSZ + lane * 8 + (size_t)spl * 32768;
  const u16* Vp = Vf + (size_t)(b * KVH + kvh) * KVSZ + lane * 8 + (size_t)spl * 32768;

  // Q as B-fragment: col = t = lane&31, k = kf*16 + hi*8 + j (Q pre-scaled)
  bf16x8 qf[4];
#pragma unroll
  for (int kf = 0; kf < 4; ++kf)
    qf[kf] = *reinterpret_cast<const bf16x8*>(Qh + kf * 16);

  f32x16 oacc[2];
#pragma unroll
  for (int df = 0; df < 2; ++df)
#pragma unroll
    for (int r = 0; r < 16; ++r) oacc[df][r] = 0.f;
  float lp = 0.f;

  // preload K fragments for tile 0 (both 32-key halves)
  bf16x8 kfr[2][4];
#pragma unroll
  for (int sb = 0; sb < 2; ++sb)
#pragma unroll
    for (int kf = 0; kf < 4; ++kf)
      kfr[sb][kf] = *reinterpret_cast<const bf16x8*>(Kp + sb * 2048 + kf * 512);

  for (int it = 0; it < 8; ++it, Kp += 4096, Vp += 4096) {
    // ---- QK^T from pre-loaded fragments ----
    f32x16 sacc[2];
#pragma unroll
    for (int sb = 0; sb < 2; ++sb) {
#pragma unroll
      for (int r = 0; r < 16; ++r) sacc[sb][r] = 0.f;
    }
    __builtin_amdgcn_s_setprio(1);
#pragma unroll
    for (int sb = 0; sb < 2; ++sb)
#pragma unroll
      for (int kf = 0; kf < 4; ++kf)
        sacc[sb] = __builtin_amdgcn_mfma_f32_32x32x16_bf16(kfr[sb][kf], qf[kf], sacc[sb], 0, 0, 0);
    __builtin_amdgcn_s_setprio(0);

    // ---- issue V(cur) now: hides under softmax + pack ----
    bf16x8 vf[2][2][2];  // [df][sb][ks]
#pragma unroll
    for (int df = 0; df < 2; ++df)
#pragma unroll
      for (int sb = 0; sb < 2; ++sb)
#pragma unroll
        for (int ks = 0; ks < 2; ++ks)
          vf[df][sb][ks] =
              *reinterpret_cast<const bf16x8*>(Vp + (size_t)(df * 4 + sb * 2 + ks) * 512);

    // ---- issue K(next) now: hides under softmax + pack + PV ----
    if (it < 7) {
#pragma unroll
      for (int sb = 0; sb < 2; ++sb)
#pragma unroll
        for (int kf = 0; kf < 4; ++kf)
          kfr[sb][kf] =
              *reinterpret_cast<const bf16x8*>(Kp + 4096 + sb * 2048 + kf * 512);
    }

    // ---- static-max softmax: P = 2^s straight from MFMA output ----
    float a0 = 0.f, a1 = 0.f, a2 = 0.f, a3 = 0.f;
#pragma unroll
    for (int sb = 0; sb < 2; ++sb)
#pragma unroll
      for (int r = 0; r < 16; r += 4) {
        float e0 = exp2r(sacc[sb][r]);
        float e1 = exp2r(sacc[sb][r + 1]);
        float e2 = exp2r(sacc[sb][r + 2]);
        float e3 = exp2r(sacc[sb][r + 3]);
        sacc[sb][r] = e0; sacc[sb][r + 1] = e1; sacc[sb][r + 2] = e2; sacc[sb][r + 3] = e3;
        a0 += e0; a1 += e1; a2 += e2; a3 += e3;
      }
    lp += (a0 + a1) + (a2 + a3);

    // ---- pack P to B-frag layout via v_permlane32_swap_b32 ----
    bf16x8 pf[2][2];  // [sb][ks]
#pragma unroll
    for (int sb = 0; sb < 2; ++sb) {
      u32 pw[8];
#pragma unroll
      for (int r2 = 0; r2 < 8; ++r2) {
        u32 o;
        asm("v_cvt_pk_bf16_f32 %0, %1, %2"
            : "=v"(o)
            : "v"(sacc[sb][2 * r2]), "v"(sacc[sb][2 * r2 + 1]));
        pw[r2] = o;
      }
      u32 fw[2][4];
#pragma unroll
      for (int pp = 0; pp < 4; ++pp) {
        int ks = pp >> 1, o = pp & 1;
        u32 a = pw[ks * 4 + o], bq = pw[ks * 4 + o + 2];
        // A' = {A_lo | B_lo}, B' = {A_hi | B_hi}
        asm("v_permlane32_swap_b32 %0, %1" : "+v"(a), "+v"(bq));
        fw[ks][o] = a;
        fw[ks][o + 2] = bq;
      }
#pragma unroll
      for (int ks = 0; ks < 2; ++ks) {
        i32x4 iv = {(int)fw[ks][0], (int)fw[ks][1], (int)fw[ks][2], (int)fw[ks][3]};
        pf[sb][ks] = __builtin_bit_cast(bf16x8, iv);
      }
    }

    // ---- O^T += Vt * P^T (vf issued ~400 cycles ago) ----
    __builtin_amdgcn_s_setprio(1);
#pragma unroll
    for (int df = 0; df < 2; ++df)
#pragma unroll
      for (int sb = 0; sb < 2; ++sb)
#pragma unroll
        for (int ks = 0; ks < 2; ++ks)
          oacc[df] =
              __builtin_amdgcn_mfma_f32_32x32x16_bf16(vf[df][sb][ks], pf[sb][ks], oacc[df], 0, 0, 0);
    __builtin_amdgcn_s_setprio(0);
  }

  // ---- sequential split merge (pure sums): spl 1..3 publish; spl 0 adds ----
  lp += __shfl_xor(lp, 32);  // both lane-halves now hold this split's full l

  for (int src = 1; src < 4; ++src) {
    if (spl == src) {
      float* cb = &cmb[qsub][l31][0];
#pragma unroll
      for (int df = 0; df < 2; ++df)
#pragma unroll
        for (int r = 0; r < 16; ++r) {
          int d = df * 32 + (r & 3) + 8 * (r >> 2) + 4 * hi;
          cb[d] = oacc[df][r];
        }
      if (hi == 0) cb[64] = lp;
    }
    __syncthreads();
    if (spl == 0) {
      const float* cb = &cmb[qsub][l31][0];
      lp += cb[64];
#pragma unroll
      for (int df = 0; df < 2; ++df)
#pragma unroll
        for (int r = 0; r < 16; ++r) {
          int d = df * 32 + (r & 3) + 8 * (r >> 2) + 4 * hi;
          oacc[df][r] += cb[d];
        }
    }
    __syncthreads();  // WAR: publisher slot reused next round
  }

  if (spl == 0) {  // normalize + stage final bf16 O for coalesced store
    float linv = 1.0f / lp;
#pragma unroll
    for (int df = 0; df < 2; ++df)
#pragma unroll
      for (int r = 0; r < 16; ++r) {
        int d = df * 32 + (r & 3) + 8 * (r >> 2) + 4 * hi;
        ot[qsub][l31][d] = f2bf(oacc[df][r] * linv);
      }
  }
  __syncthreads();
  if (spl == 0) {
    int tr = lane >> 1, dblk = (lane & 1) * 32;
    u16* gdst = Oa + ((size_t)(b * Tt + t0 + tr)) * Dd + h * HD + dblk;
#pragma unroll
    for (int c = 0; c < 4; ++c) {
      ushort8v vv = *reinterpret_cast<const ushort8v*>(&ot[qsub][tr][dblk + c * 8]);
      *reinterpret_cast<ushort8v*>(gdst + c * 8) = vv;
    }
  }
}

// ---------------------------------------------------------------- launch
extern "C" void kernel_launch(void* const* d_in, const int* in_sizes, int n_in, void* d_out,
                              int out_size, void* d_ws, size_t ws_size, hipStream_t stream) {
  (void)in_sizes; (void)n_in; (void)out_size; (void)ws_size;
  const float* x = (const float*)d_in[0];
  const float* cosT = (const float*)d_in[1];
  const float* sinT = (const float*)d_in[2];
  const float* Wq = (const float*)d_in[3];
  const float* Wkv = (const float*)d_in[4];
  const float* Wo = (const float*)d_in[5];

  char* p = (char*)d_ws;
  u16* xb = (u16*)p;   p += (size_t)4096 * 1024 * 2;
  u16* wqkv = (u16*)p; p += (size_t)1536 * 1024 * 2;
  u16* wob = (u16*)p;  p += (size_t)1024 * 1024 * 2;
  u16* Pbuf = (u16*)p; p += (size_t)4096 * 1536 * 2;
  u16* Qb = (u16*)p;   p += (size_t)Bb * QH * Tt * HD * 2;
  u16* Kbuf = (u16*)p; p += (size_t)Bb * KVH * Tt * HD * 2;
  u16* Vfb = (u16*)p;  p += (size_t)Bb * KVH * HD * Tt * 2;
  u16* Ob = Pbuf;  // Pbuf dead after rope_scatter + v_transpose

  cvt_all<<<6656, 256, 0, stream>>>(x, Wq, Wkv, Wo, xb, wqkv, wob);
  gemm_bt<false><<<dim3(12, 32), 256, 0, stream>>>(xb, wqkv, Pbuf, 4096, 1536, 1024);
  rope_scatter<<<10240, 256, 0, stream>>>(Pbuf, cosT, sinT, Qb, Kbuf);
  v_transpose<<<dim3(32, 8), 256, 0, stream>>>(Pbuf, Vfb);
  attn_fwd8<<<1024, 512, 0, stream>>>(Qb, Kbuf, Vfb, Ob);
  gemm_bt<true><<<dim3(8, 32), 256, 0, stream>>>(Ob, wob, d_out, 4096, 1024, 1024);
}

// Round 9
// 123.222 us; speedup vs baseline: 1.4675x; 1.4675x over previous
//
#include <hip/hip_runtime.h>

// GQA attention fused pipeline for MI355X (gfx950).
// cvt(fused) -> GEMM(QKV, global_load_lds staging) -> RoPE/scatter (K
// fragment-major) + V-transpose (fragment-major) -> flash attention (swapped
// 32x32 MFMA, split-K x4, static-max softmax, V-early issue, NO cross-tile
// register prefetch) -> GEMM(out, global_load_lds staging).

typedef __bf16 bf16x8 __attribute__((ext_vector_type(8)));
typedef float f32x4 __attribute__((ext_vector_type(4)));
typedef float f32x16 __attribute__((ext_vector_type(16)));
typedef int i32x4 __attribute__((ext_vector_type(4)));
typedef unsigned short ushort4v __attribute__((ext_vector_type(4)));
typedef unsigned short ushort8v __attribute__((ext_vector_type(8)));
typedef unsigned short u16;
typedef unsigned int u32;

#define DEVINL __device__ __forceinline__

DEVINL float bf2f(u16 u) {
  unsigned int x = ((unsigned int)u) << 16;
  return __builtin_bit_cast(float, x);
}
DEVINL u16 f2bf(float f) {  // RTNE
  unsigned int x = __builtin_bit_cast(unsigned int, f);
  x += 0x7fffu + ((x >> 16) & 1u);
  return (u16)(x >> 16);
}
// raw 2^x — single v_exp_f32, skips OCML range-guard sequence
DEVINL float exp2r(float x) {
  float r;
  asm("v_exp_f32 %0, %1" : "=v"(r) : "v"(x));
  return r;
}
// async global->LDS, 16B per lane; LDS dest = wave-uniform base + lane*16
DEVINL void gld16(const u16* g, u16* l) {
  __builtin_amdgcn_global_load_lds(
      (const __attribute__((address_space(1))) void*)g,
      (__attribute__((address_space(3))) void*)l, 16, 0, 0);
}

constexpr int Bb = 2, Tt = 2048, Dd = 1024, QH = 16, KVH = 4, HD = 64;
// fold softmax scale (1/sqrt(64)) and log2(e) into Q so we can use exp2
constexpr float SCALE_L2E = 0.125f * 1.44269504088896340736f;
// per-(b,kvh) fragment-major K/V extent: 2048 keys * 64 dims
constexpr int KVSZ = 131072;

// ---------------------------------------------------------------- fused convert
__global__ void cvt_all(const float* __restrict__ x, const float* __restrict__ Wq,
                        const float* __restrict__ Wkv, const float* __restrict__ Wo,
                        u16* __restrict__ xb, u16* __restrict__ wqkv,
                        u16* __restrict__ wob) {
  int i = blockIdx.x * 256 + threadIdx.x;  // grid covers 1,703,936 float4s exactly
  const float* src;
  u16* dst;
  if (i < 1048576) {
    src = x; dst = xb;
  } else if (i < 1310720) {
    src = Wq - (size_t)1048576 * 4; dst = wqkv - (size_t)1048576 * 4;
  } else if (i < 1441792) {
    src = Wkv - (size_t)1310720 * 4; dst = wqkv + (size_t)1024 * 1024 - (size_t)1310720 * 4;
  } else {
    src = Wo - (size_t)1441792 * 4; dst = wob - (size_t)1441792 * 4;
  }
  float4 v = reinterpret_cast<const float4*>(src)[i];
  ushort4v o = {f2bf(v.x), f2bf(v.y), f2bf(v.z), f2bf(v.w)};
  *reinterpret_cast<ushort4v*>(dst + (size_t)i * 4) = o;
}

// ---------------------------------------------------------------- GEMM C = A(M,K) @ B(N,K)^T
// m97 2-phase structure: global_load_lds width-16 staging (linear LDS), then
// ds_read_b128 fragment reads + 16x16x32 MFMA. 128x128 tile, BK=64, 4 waves.
template <bool OUT_F32>
__global__ __launch_bounds__(256) void gemm_bt(const u16* __restrict__ A,
                                               const u16* __restrict__ Bw,
                                               void* __restrict__ Cout, int M, int N, int K) {
  __shared__ alignas(16) u16 lA[128 * 64];
  __shared__ alignas(16) u16 lB[128 * 64];
  const int tid = threadIdx.x;
  const int w = tid >> 6, lane = tid & 63;
  const int r16 = lane & 15, g4 = lane >> 4;
  const int row0 = blockIdx.y * 128, col0 = blockIdx.x * 128;
  const int sr = tid >> 3, sc = tid & 7;  // lane l of wave w: sr=w*8+(l>>3), sc=l&7
  const int NT = K >> 6;
  const int wm = (w >> 1) * 64, wn = (w & 1) * 64;

  f32x4 acc[4][4];
#pragma unroll
  for (int i = 0; i < 4; ++i)
#pragma unroll
    for (int j = 0; j < 4; ++j) acc[i][j] = f32x4{0.f, 0.f, 0.f, 0.f};

  // per-lane global source cursors; wave-uniform LDS bases (dest = base + lane*16B)
  const u16* Ap = A + (size_t)(row0 + sr) * K + sc * 8;
  const u16* Bp = Bw + (size_t)(col0 + sr) * K + sc * 8;
  u16* lAb = &lA[(size_t)(w * 8) * 64];
  u16* lBb = &lB[(size_t)(w * 8) * 64];

  for (int kt = 0; kt < NT; ++kt) {
    __syncthreads();  // all waves done reading LDS from previous step
    const int k0 = kt << 6;
#pragma unroll
    for (int i = 0; i < 4; ++i) {
      gld16(Ap + (size_t)(i * 32) * K + k0, lAb + i * 32 * 64);
      gld16(Bp + (size_t)(i * 32) * K + k0, lBb + i * 32 * 64);
    }
    __syncthreads();  // compiler drains vmcnt(0) before barrier -> LDS ready
#pragma unroll
    for (int kk = 0; kk < 2; ++kk) {
      bf16x8 af[4], bfr[4];
#pragma unroll
      for (int mf = 0; mf < 4; ++mf)
        af[mf] = *reinterpret_cast<const bf16x8*>(
            &lA[(wm + mf * 16 + r16) * 64 + (kk * 4 + g4) * 8]);
#pragma unroll
      for (int nf = 0; nf < 4; ++nf)
        bfr[nf] = *reinterpret_cast<const bf16x8*>(
            &lB[(wn + nf * 16 + r16) * 64 + (kk * 4 + g4) * 8]);
#pragma unroll
      for (int mf = 0; mf < 4; ++mf)
#pragma unroll
        for (int nf = 0; nf < 4; ++nf)
          acc[mf][nf] =
              __builtin_amdgcn_mfma_f32_16x16x32_bf16(af[mf], bfr[nf], acc[mf][nf], 0, 0, 0);
    }
  }

#pragma unroll
  for (int mf = 0; mf < 4; ++mf)
#pragma unroll
    for (int nf = 0; nf < 4; ++nf)
#pragma unroll
      for (int r = 0; r < 4; ++r) {
        size_t row = (size_t)(row0 + wm + mf * 16 + g4 * 4 + r);
        size_t col = (size_t)(col0 + wn + nf * 16 + r16);
        float v = acc[mf][nf][r];
        if (OUT_F32)
          reinterpret_cast<float*>(Cout)[row * N + col] = v;
        else
          reinterpret_cast<u16*>(Cout)[row * N + col] = f2bf(v);
      }
}

// ---------------------------------------------------------------- RoPE + scatter
// Q row-major. K written FRAGMENT-MAJOR:
//   elem K[bh][t][d] -> bh*KVSZ + ((t>>5)*4 + (d>>4))*512
//                       + (((d>>3)&1)*32 + (t&31))*8 + (d&7)
__global__ void rope_scatter(const u16* __restrict__ P, const float* __restrict__ cosT,
                             const float* __restrict__ sinT, u16* __restrict__ Q,
                             u16* __restrict__ Kc) {
  int idx = blockIdx.x * 256 + threadIdx.x;
  if (idx >= (Bb * Tt) * 640) return;
  int row = idx / 640, p = idx - row * 640;
  int b = row >> 11, t = row & 2047;
  int n, d;
  u16* outp;
  float scl;
  if (p < 512) {
    n = p * 2;
    int h = n >> 6;
    d = n & 63;
    outp = Q + ((size_t)(b * QH + h) * Tt + t) * HD + d;
    scl = SCALE_L2E;
  } else {
    int r2 = p - 512;
    int kvh = r2 >> 5, dp = r2 & 31;
    d = dp * 2;
    n = 1024 + kvh * 128 + d;
    int bh = b * KVH + kvh;
    int kf = d >> 4, h8 = (d >> 3) & 1, j = d & 7;  // j even
    outp = Kc + (size_t)bh * KVSZ + ((t >> 5) * 4 + kf) * 512 + (h8 * 32 + (t & 31)) * 8 + j;
    scl = 1.0f;
  }
  unsigned int pv = *reinterpret_cast<const unsigned int*>(P + (size_t)row * 1536 + n);
  float v0 = bf2f((u16)(pv & 0xffffu)), v1 = bf2f((u16)(pv >> 16));
  float c = cosT[t * HD + d], s = sinT[t * HD + d];
  float o0 = (v0 * c - v1 * s) * scl;
  float o1 = (v1 * c + v0 * s) * scl;
  unsigned int ob = (unsigned int)f2bf(o0) | ((unsigned int)f2bf(o1) << 16);
  *reinterpret_cast<unsigned int*>(outp) = ob;
}

// ---------------------------------------------------------------- V transpose -> fragment-major
__global__ void v_transpose(const u16* __restrict__ P, u16* __restrict__ Vf) {
  __shared__ u16 tile[64][72];
  int bh = blockIdx.y;
  int b = bh >> 2, kvh = bh & 3;
  int t0 = blockIdx.x * 64;
  int tid = threadIdx.x;
  int colbase = 1024 + kvh * 128 + 64;
#pragma unroll
  for (int j = 0; j < 4; ++j) {
    int rr = j * 16 + (tid >> 4);
    int cc = (tid & 15) * 4;
    *reinterpret_cast<uint2*>(&tile[rr][cc]) =
        *reinterpret_cast<const uint2*>(P + (size_t)(b * Tt + t0 + rr) * 1536 + colbase + cc);
  }
  __syncthreads();
#pragma unroll
  for (int kk = 0; kk < 2; ++kk) {
    int CH = kk * 256 + tid;            // 512 chunks of 16B
    int df = CH >> 8, sbks = (CH >> 6) & 3, h8 = (CH >> 5) & 1, l = CH & 31;
    int d = df * 32 + l;
    int c = (sbks >> 1) * 4 + (sbks & 1) * 2 + h8;  // s-chunk within the 64-key tile
    ushort8v v;
#pragma unroll
    for (int j = 0; j < 8; ++j) v[j] = tile[c * 8 + j][d];
    u16* dst = Vf + (size_t)bh * KVSZ + (((t0 >> 6) * 2 + df) * 4 + sbks) * 512 +
               (h8 * 32 + l) * 8;
    *reinterpret_cast<ushort8v*>(dst) = v;
  }
}

// ---------------------------------------------------------------- flash attention v9
// v7 structure (8 waves = {spl 0..3}x{qsub 0..1}, static-max softmax, permlane
// pack, pure-sum merge) + v5's spill-free load schedule: all K fragments for
// the tile load at the top (8 loads in flight), V fragments issue right after
// the QK MFMAs (hide under exp+pack). NO register prefetch across the loop
// back-edge (r8's spill). Peak live ~100 regs.
__global__ __launch_bounds__(512, 4) void attn_fwd9(const u16* __restrict__ Q,
                                                    const u16* __restrict__ Kf,
                                                    const u16* __restrict__ Vf,
                                                    u16* __restrict__ Oa) {
  __shared__ alignas(16) float cmb[2][32][66];  // publish slot: O^T(64) + l
  __shared__ alignas(16) u16 ot[2][32][72];     // final bf16 O, pre-store transpose
  const int tid = threadIdx.x;
  const int w = tid >> 6, lane = tid & 63;
  const int qsub = w & 1, spl = w >> 1;
  const int l31 = lane & 31, hi = lane >> 5;

  const int fid = blockIdx.x;
  const int xcd = fid & 7, idx = fid >> 3;     // xcd == (b,kvh): K/V L2-resident
  const int b = xcd >> 2, kvh = xcd & 3;
  const int g = idx & 3, qblk = idx >> 2;
  const int h = kvh * 4 + g;
  const int t0 = qblk * 64 + qsub * 32;

  const u16* Qh = Q + ((size_t)(b * QH + h) * Tt + t0 + l31) * HD + hi * 8;
  // per-wave K/V cursors advance 4096 elements per 64-key tile
  const u16* Kp = Kf + (size_t)(b * KVH + kvh) * KVSZ + lane * 8 + (size_t)spl * 32768;
  const u16* Vp = Vf + (size_t)(b * KVH + kvh) * KVSZ + lane * 8 + (size_t)spl * 32768;

  // Q as B-fragment: col = t = lane&31, k = kf*16 + hi*8 + j (Q pre-scaled)
  bf16x8 qf[4];
#pragma unroll
  for (int kf = 0; kf < 4; ++kf)
    qf[kf] = *reinterpret_cast<const bf16x8*>(Qh + kf * 16);

  f32x16 oacc[2];
#pragma unroll
  for (int df = 0; df < 2; ++df)
#pragma unroll
    for (int r = 0; r < 16; ++r) oacc[df][r] = 0.f;
  float lp = 0.f;

  for (int it = 0; it < 8; ++it, Kp += 4096, Vp += 4096) {
    // ---- all K fragments for this tile: 8 independent loads in flight ----
    bf16x8 kfr[2][4];
#pragma unroll
    for (int sb = 0; sb < 2; ++sb)
#pragma unroll
      for (int kf = 0; kf < 4; ++kf)
        kfr[sb][kf] = *reinterpret_cast<const bf16x8*>(Kp + sb * 2048 + kf * 512);

    // ---- QK^T (kfr dies here) ----
    f32x16 sacc[2];
#pragma unroll
    for (int sb = 0; sb < 2; ++sb)
#pragma unroll
      for (int r = 0; r < 16; ++r) sacc[sb][r] = 0.f;
    __builtin_amdgcn_s_setprio(1);
#pragma unroll
    for (int sb = 0; sb < 2; ++sb)
#pragma unroll
      for (int kf = 0; kf < 4; ++kf)
        sacc[sb] = __builtin_amdgcn_mfma_f32_32x32x16_bf16(kfr[sb][kf], qf[kf], sacc[sb], 0, 0, 0);
    __builtin_amdgcn_s_setprio(0);

    // ---- V issued NOW: round-trip hides under exp + pack (~300 cyc VALU) ----
    bf16x8 vf[2][2][2];  // [df][sb][ks]
#pragma unroll
    for (int df = 0; df < 2; ++df)
#pragma unroll
      for (int sb = 0; sb < 2; ++sb)
#pragma unroll
        for (int ks = 0; ks < 2; ++ks)
          vf[df][sb][ks] =
              *reinterpret_cast<const bf16x8*>(Vp + (size_t)(df * 4 + sb * 2 + ks) * 512);

    // ---- static-max softmax: P = 2^s straight from MFMA output ----
    float a0 = 0.f, a1 = 0.f, a2 = 0.f, a3 = 0.f;
#pragma unroll
    for (int sb = 0; sb < 2; ++sb)
#pragma unroll
      for (int r = 0; r < 16; r += 4) {
        float e0 = exp2r(sacc[sb][r]);
        float e1 = exp2r(sacc[sb][r + 1]);
        float e2 = exp2r(sacc[sb][r + 2]);
        float e3 = exp2r(sacc[sb][r + 3]);
        sacc[sb][r] = e0; sacc[sb][r + 1] = e1; sacc[sb][r + 2] = e2; sacc[sb][r + 3] = e3;
        a0 += e0; a1 += e1; a2 += e2; a3 += e3;
      }
    lp += (a0 + a1) + (a2 + a3);

    // ---- pack P to B-frag layout via v_permlane32_swap_b32 ----
    bf16x8 pf[2][2];  // [sb][ks]
#pragma unroll
    for (int sb = 0; sb < 2; ++sb) {
      u32 pw[8];
#pragma unroll
      for (int r2 = 0; r2 < 8; ++r2) {
        u32 o;
        asm("v_cvt_pk_bf16_f32 %0, %1, %2"
            : "=v"(o)
            : "v"(sacc[sb][2 * r2]), "v"(sacc[sb][2 * r2 + 1]));
        pw[r2] = o;
      }
      u32 fw[2][4];
#pragma unroll
      for (int pp = 0; pp < 4; ++pp) {
        int ks = pp >> 1, o = pp & 1;
        u32 a = pw[ks * 4 + o], bq = pw[ks * 4 + o + 2];
        // A' = {A_lo | B_lo}, B' = {A_hi | B_hi}
        asm("v_permlane32_swap_b32 %0, %1" : "+v"(a), "+v"(bq));
        fw[ks][o] = a;
        fw[ks][o + 2] = bq;
      }
#pragma unroll
      for (int ks = 0; ks < 2; ++ks) {
        i32x4 iv = {(int)fw[ks][0], (int)fw[ks][1], (int)fw[ks][2], (int)fw[ks][3]};
        pf[sb][ks] = __builtin_bit_cast(bf16x8, iv);
      }
    }

    // ---- O^T += Vt * P^T (vf issued ~300+ cycles ago) ----
    __builtin_amdgcn_s_setprio(1);
#pragma unroll
    for (int df = 0; df < 2; ++df)
#pragma unroll
      for (int sb = 0; sb < 2; ++sb)
#pragma unroll
        for (int ks = 0; ks < 2; ++ks)
          oacc[df] =
              __builtin_amdgcn_mfma_f32_32x32x16_bf16(vf[df][sb][ks], pf[sb][ks], oacc[df], 0, 0, 0);
    __builtin_amdgcn_s_setprio(0);
  }

  // ---- sequential split merge (pure sums): spl 1..3 publish; spl 0 adds ----
  lp += __shfl_xor(lp, 32);  // both lane-halves now hold this split's full l

  for (int src = 1; src < 4; ++src) {
    if (spl == src) {
      float* cb = &cmb[qsub][l31][0];
#pragma unroll
      for (int df = 0; df < 2; ++df)
#pragma unroll
        for (int r = 0; r < 16; ++r) {
          int d = df * 32 + (r & 3) + 8 * (r >> 2) + 4 * hi;
          cb[d] = oacc[df][r];
        }
      if (hi == 0) cb[64] = lp;
    }
    __syncthreads();
    if (spl == 0) {
      const float* cb = &cmb[qsub][l31][0];
      lp += cb[64];
#pragma unroll
      for (int df = 0; df < 2; ++df)
#pragma unroll
        for (int r = 0; r < 16; ++r) {
          int d = df * 32 + (r & 3) + 8 * (r >> 2) + 4 * hi;
          oacc[df][r] += cb[d];
        }
    }
    __syncthreads();  // WAR: publisher slot reused next round
  }

  if (spl == 0) {  // normalize + stage final bf16 O for coalesced store
    float linv = 1.0f / lp;
#pragma unroll
    for (int df = 0; df < 2; ++df)
#pragma unroll
      for (int r = 0; r < 16; ++r) {
        int d = df * 32 + (r & 3) + 8 * (r >> 2) + 4 * hi;
        ot[qsub][l31][d] = f2bf(oacc[df][r] * linv);
      }
  }
  __syncthreads();
  if (spl == 0) {
    int tr = lane >> 1, dblk = (lane & 1) * 32;
    u16* gdst = Oa + ((size_t)(b * Tt + t0 + tr)) * Dd + h * HD + dblk;
#pragma unroll
    for (int c = 0; c < 4; ++c) {
      ushort8v vv = *reinterpret_cast<const ushort8v*>(&ot[qsub][tr][dblk + c * 8]);
      *reinterpret_cast<ushort8v*>(gdst + c * 8) = vv;
    }
  }
}

// ---------------------------------------------------------------- launch
extern "C" void kernel_launch(void* const* d_in, const int* in_sizes, int n_in, void* d_out,
                              int out_size, void* d_ws, size_t ws_size, hipStream_t stream) {
  (void)in_sizes; (void)n_in; (void)out_size; (void)ws_size;
  const float* x = (const float*)d_in[0];
  const float* cosT = (const float*)d_in[1];
  const float* sinT = (const float*)d_in[2];
  const float* Wq = (const float*)d_in[3];
  const float* Wkv = (const float*)d_in[4];
  const float* Wo = (const float*)d_in[5];

  char* p = (char*)d_ws;
  u16* xb = (u16*)p;   p += (size_t)4096 * 1024 * 2;
  u16* wqkv = (u16*)p; p += (size_t)1536 * 1024 * 2;
  u16* wob = (u16*)p;  p += (size_t)1024 * 1024 * 2;
  u16* Pbuf = (u16*)p; p += (size_t)4096 * 1536 * 2;
  u16* Qb = (u16*)p;   p += (size_t)Bb * QH * Tt * HD * 2;
  u16* Kbuf = (u16*)p; p += (size_t)Bb * KVH * Tt * HD * 2;
  u16* Vfb = (u16*)p;  p += (size_t)Bb * KVH * HD * Tt * 2;
  u16* Ob = Pbuf;  // Pbuf dead after rope_scatter + v_transpose

  cvt_all<<<6656, 256, 0, stream>>>(x, Wq, Wkv, Wo, xb, wqkv, wob);
  gemm_bt<false><<<dim3(12, 32), 256, 0, stream>>>(xb, wqkv, Pbuf, 4096, 1536, 1024);
  rope_scatter<<<10240, 256, 0, stream>>>(Pbuf, cosT, sinT, Qb, Kbuf);
  v_transpose<<<dim3(32, 8), 256, 0, stream>>>(Pbuf, Vfb);
  attn_fwd9<<<1024, 512, 0, stream>>>(Qb, Kbuf, Vfb, Ob);
  gemm_bt<true><<<dim3(8, 32), 256, 0, stream>>>(Ob, wob, d_out, 4096, 1024, 1024);
}

// Round 10
// 107.419 us; speedup vs baseline: 1.6833x; 1.1471x over previous
//
#include <hip/hip_runtime.h>

// GQA attention fused pipeline for MI355X (gfx950).
// cvt(fused) -> GEMM(QKV, reg-staged prefetch) -> fused RoPE/scatter +
// V-transpose (both fragment-major) -> flash attention (swapped 32x32 MFMA,
// split-K x4, static-max softmax) -> GEMM(out, BN=64 for 2 blocks/CU).

typedef __bf16 bf16x8 __attribute__((ext_vector_type(8)));
typedef float f32x4 __attribute__((ext_vector_type(4)));
typedef float f32x16 __attribute__((ext_vector_type(16)));
typedef int i32x4 __attribute__((ext_vector_type(4)));
typedef unsigned short ushort4v __attribute__((ext_vector_type(4)));
typedef unsigned short ushort8v __attribute__((ext_vector_type(8)));
typedef unsigned short u16;
typedef unsigned int u32;

#define DEVINL __device__ __forceinline__

DEVINL float bf2f(u16 u) {
  unsigned int x = ((unsigned int)u) << 16;
  return __builtin_bit_cast(float, x);
}
DEVINL u16 f2bf(float f) {  // RTNE
  unsigned int x = __builtin_bit_cast(unsigned int, f);
  x += 0x7fffu + ((x >> 16) & 1u);
  return (u16)(x >> 16);
}
// raw 2^x — single v_exp_f32, skips OCML range-guard sequence
DEVINL float exp2r(float x) {
  float r;
  asm("v_exp_f32 %0, %1" : "=v"(r) : "v"(x));
  return r;
}

constexpr int Bb = 2, Tt = 2048, Dd = 1024, QH = 16, KVH = 4, HD = 64;
// fold softmax scale (1/sqrt(64)) and log2(e) into Q so we can use exp2
constexpr float SCALE_L2E = 0.125f * 1.44269504088896340736f;
// per-(b,kvh) fragment-major K/V extent: 2048 keys * 64 dims
constexpr int KVSZ = 131072;

// ---------------------------------------------------------------- fused convert
__global__ void cvt_all(const float* __restrict__ x, const float* __restrict__ Wq,
                        const float* __restrict__ Wkv, const float* __restrict__ Wo,
                        u16* __restrict__ xb, u16* __restrict__ wqkv,
                        u16* __restrict__ wob) {
  int i = blockIdx.x * 256 + threadIdx.x;  // grid covers 1,703,936 float4s exactly
  const float* src;
  u16* dst;
  if (i < 1048576) {
    src = x; dst = xb;
  } else if (i < 1310720) {
    src = Wq - (size_t)1048576 * 4; dst = wqkv - (size_t)1048576 * 4;
  } else if (i < 1441792) {
    src = Wkv - (size_t)1310720 * 4; dst = wqkv + (size_t)1024 * 1024 - (size_t)1310720 * 4;
  } else {
    src = Wo - (size_t)1441792 * 4; dst = wob - (size_t)1441792 * 4;
  }
  float4 v = reinterpret_cast<const float4*>(src)[i];
  ushort4v o = {f2bf(v.x), f2bf(v.y), f2bf(v.z), f2bf(v.w)};
  *reinterpret_cast<ushort4v*>(dst + (size_t)i * 4) = o;
}

// ---------------------------------------------------------------- GEMM C = A(M,K) @ B(N,K)^T
// r7 reg-staged prefetch structure (self-hides global latency). BM=128 rows,
// BN = BNF*32 cols (BNF=4 -> 128, BNF=2 -> 64 for small-grid occupancy).
// 4 waves, each 64 x BN/2; XOR-swizzled LDS chunks for conflict-free ds_read.
template <bool OUT_F32, int BNF>
__global__ __launch_bounds__(256) void gemm_bt(const u16* __restrict__ A,
                                               const u16* __restrict__ Bw,
                                               void* __restrict__ Cout, int M, int N, int K) {
  __shared__ alignas(16) u16 lA[128 * 64];
  __shared__ alignas(16) u16 lB[BNF * 32 * 64];
  const int tid = threadIdx.x;
  const int w = tid >> 6, lane = tid & 63;
  const int r16 = lane & 15, g4 = lane >> 4;
  const int row0 = blockIdx.y * 128, col0 = blockIdx.x * (BNF * 32);
  const int sr = tid >> 3, sc = tid & 7;
  const int NT = K >> 6;

  bf16x8 ra[4], rb[BNF];
  f32x4 acc[4][BNF];
#pragma unroll
  for (int i = 0; i < 4; ++i)
#pragma unroll
    for (int j = 0; j < BNF; ++j) acc[i][j] = f32x4{0.f, 0.f, 0.f, 0.f};

  const int wm = (w >> 1) * 64, wn = (w & 1) * (BNF * 8);  // BNF*8 = (BN/2)/2... (16*BNF/2)

#pragma unroll
  for (int i = 0; i < 4; ++i) {
    int r = i * 32 + sr;
    ra[i] = *reinterpret_cast<const bf16x8*>(A + (size_t)(row0 + r) * K + sc * 8);
  }
#pragma unroll
  for (int i = 0; i < BNF; ++i) {
    int r = i * 32 + sr;
    rb[i] = *reinterpret_cast<const bf16x8*>(Bw + (size_t)(col0 + r) * K + sc * 8);
  }

  for (int kt = 0; kt < NT; ++kt) {
    __syncthreads();
#pragma unroll
    for (int i = 0; i < 4; ++i) {
      int r = i * 32 + sr;
      int c = (sc ^ (r & 7)) * 8;
      *reinterpret_cast<bf16x8*>(&lA[r * 64 + c]) = ra[i];
    }
#pragma unroll
    for (int i = 0; i < BNF; ++i) {
      int r = i * 32 + sr;
      int c = (sc ^ (r & 7)) * 8;
      *reinterpret_cast<bf16x8*>(&lB[r * 64 + c]) = rb[i];
    }
    __syncthreads();
    if (kt + 1 < NT) {  // prefetch next k-tile into regs; overlaps MFMA below
      int k0 = (kt + 1) << 6;
#pragma unroll
      for (int i = 0; i < 4; ++i) {
        int r = i * 32 + sr;
        ra[i] = *reinterpret_cast<const bf16x8*>(A + (size_t)(row0 + r) * K + k0 + sc * 8);
      }
#pragma unroll
      for (int i = 0; i < BNF; ++i) {
        int r = i * 32 + sr;
        rb[i] = *reinterpret_cast<const bf16x8*>(Bw + (size_t)(col0 + r) * K + k0 + sc * 8);
      }
    }
#pragma unroll
    for (int kk = 0; kk < 2; ++kk) {
      bf16x8 af[4], bfr[BNF];
#pragma unroll
      for (int mf = 0; mf < 4; ++mf) {
        int r = wm + mf * 16 + r16;
        int c = ((kk * 4 + g4) ^ (r & 7)) * 8;
        af[mf] = *reinterpret_cast<const bf16x8*>(&lA[r * 64 + c]);
      }
#pragma unroll
      for (int nf = 0; nf < BNF; ++nf) {
        int r = wn * 2 + nf * 16 + r16;  // wn*2 = (w&1)*BNF*16
        int c = ((kk * 4 + g4) ^ (r & 7)) * 8;
        bfr[nf] = *reinterpret_cast<const bf16x8*>(&lB[r * 64 + c]);
      }
#pragma unroll
      for (int mf = 0; mf < 4; ++mf)
#pragma unroll
        for (int nf = 0; nf < BNF; ++nf)
          acc[mf][nf] =
              __builtin_amdgcn_mfma_f32_16x16x32_bf16(af[mf], bfr[nf], acc[mf][nf], 0, 0, 0);
    }
  }

#pragma unroll
  for (int mf = 0; mf < 4; ++mf)
#pragma unroll
    for (int nf = 0; nf < BNF; ++nf)
#pragma unroll
      for (int r = 0; r < 4; ++r) {
        size_t row = (size_t)(row0 + wm + mf * 16 + g4 * 4 + r);
        size_t col = (size_t)(col0 + wn * 2 + nf * 16 + r16);
        float v = acc[mf][nf][r];
        if (OUT_F32)
          reinterpret_cast<float*>(Cout)[row * N + col] = v;
        else
          reinterpret_cast<u16*>(Cout)[row * N + col] = f2bf(v);
      }
}

// ---------------------------------------------------------------- fused RoPE/scatter + V-transpose
// Blocks [0,10240): RoPE q (row-major, pre-scaled) + k (fragment-major).
// Blocks [10240,10496): V transpose into fragment-major.
//   K elem [bh][t][d] -> bh*KVSZ + ((t>>5)*4+(d>>4))*512 + (((d>>3)&1)*32+(t&31))*8 + (d&7)
//   V elem [bh][d][s] -> bh*KVSZ + (((s>>6)*2+(d>>5))*4+((s>>4)&3))*512 + (((s>>3)&1)*32+(d&31))*8 + (s&7)
__global__ void rope_vt(const u16* __restrict__ P, const float* __restrict__ cosT,
                        const float* __restrict__ sinT, u16* __restrict__ Q,
                        u16* __restrict__ Kc, u16* __restrict__ Vf) {
  __shared__ u16 tile[64][72];
  const int bid = blockIdx.x;
  const int tid = threadIdx.x;
  if (bid < 10240) {
    int idx = bid * 256 + tid;
    int row = idx / 640, p = idx - row * 640;
    int b = row >> 11, t = row & 2047;
    int n, d;
    u16* outp;
    float scl;
    if (p < 512) {
      n = p * 2;
      int h = n >> 6;
      d = n & 63;
      outp = Q + ((size_t)(b * QH + h) * Tt + t) * HD + d;
      scl = SCALE_L2E;
    } else {
      int r2 = p - 512;
      int kvh = r2 >> 5, dp = r2 & 31;
      d = dp * 2;
      n = 1024 + kvh * 128 + d;
      int bh = b * KVH + kvh;
      int kf = d >> 4, h8 = (d >> 3) & 1, j = d & 7;  // j even
      outp = Kc + (size_t)bh * KVSZ + ((t >> 5) * 4 + kf) * 512 + (h8 * 32 + (t & 31)) * 8 + j;
      scl = 1.0f;
    }
    unsigned int pv = *reinterpret_cast<const unsigned int*>(P + (size_t)row * 1536 + n);
    float v0 = bf2f((u16)(pv & 0xffffu)), v1 = bf2f((u16)(pv >> 16));
    float c = cosT[t * HD + d], s = sinT[t * HD + d];
    float o0 = (v0 * c - v1 * s) * scl;
    float o1 = (v1 * c + v0 * s) * scl;
    unsigned int ob = (unsigned int)f2bf(o0) | ((unsigned int)f2bf(o1) << 16);
    *reinterpret_cast<unsigned int*>(outp) = ob;
  } else {
    int rem = bid - 10240;
    int bh = rem >> 5, tt = rem & 31;
    int b = bh >> 2, kvh = bh & 3;
    int t0 = tt * 64;
    int colbase = 1024 + kvh * 128 + 64;
#pragma unroll
    for (int j = 0; j < 4; ++j) {
      int rr = j * 16 + (tid >> 4);
      int cc = (tid & 15) * 4;
      *reinterpret_cast<uint2*>(&tile[rr][cc]) =
          *reinterpret_cast<const uint2*>(P + (size_t)(b * Tt + t0 + rr) * 1536 + colbase + cc);
    }
    __syncthreads();
#pragma unroll
    for (int kk = 0; kk < 2; ++kk) {
      int CH = kk * 256 + tid;            // 512 chunks of 16B
      int df = CH >> 8, sbks = (CH >> 6) & 3, h8 = (CH >> 5) & 1, l = CH & 31;
      int d = df * 32 + l;
      int c = (sbks >> 1) * 4 + (sbks & 1) * 2 + h8;
      ushort8v v;
#pragma unroll
      for (int j = 0; j < 8; ++j) v[j] = tile[c * 8 + j][d];
      u16* dst = Vf + (size_t)bh * KVSZ + (((t0 >> 6) * 2 + df) * 4 + sbks) * 512 +
                 (h8 * 32 + l) * 8;
      *reinterpret_cast<ushort8v*>(dst) = v;
    }
  }
}

// ---------------------------------------------------------------- flash attention (r9 structure)
__global__ __launch_bounds__(512, 4) void attn_fwd9(const u16* __restrict__ Q,
                                                    const u16* __restrict__ Kf,
                                                    const u16* __restrict__ Vf,
                                                    u16* __restrict__ Oa) {
  __shared__ alignas(16) float cmb[2][32][66];  // publish slot: O^T(64) + l
  __shared__ alignas(16) u16 ot[2][32][72];     // final bf16 O, pre-store transpose
  const int tid = threadIdx.x;
  const int w = tid >> 6, lane = tid & 63;
  const int qsub = w & 1, spl = w >> 1;
  const int l31 = lane & 31, hi = lane >> 5;

  const int fid = blockIdx.x;
  const int xcd = fid & 7, idx = fid >> 3;     // xcd == (b,kvh): K/V L2-resident
  const int b = xcd >> 2, kvh = xcd & 3;
  const int g = idx & 3, qblk = idx >> 2;
  const int h = kvh * 4 + g;
  const int t0 = qblk * 64 + qsub * 32;

  const u16* Qh = Q + ((size_t)(b * QH + h) * Tt + t0 + l31) * HD + hi * 8;
  const u16* Kp = Kf + (size_t)(b * KVH + kvh) * KVSZ + lane * 8 + (size_t)spl * 32768;
  const u16* Vp = Vf + (size_t)(b * KVH + kvh) * KVSZ + lane * 8 + (size_t)spl * 32768;

  bf16x8 qf[4];
#pragma unroll
  for (int kf = 0; kf < 4; ++kf)
    qf[kf] = *reinterpret_cast<const bf16x8*>(Qh + kf * 16);

  f32x16 oacc[2];
#pragma unroll
  for (int df = 0; df < 2; ++df)
#pragma unroll
    for (int r = 0; r < 16; ++r) oacc[df][r] = 0.f;
  float lp = 0.f;

  for (int it = 0; it < 8; ++it, Kp += 4096, Vp += 4096) {
    // ---- all K fragments for this tile: 8 independent loads in flight ----
    bf16x8 kfr[2][4];
#pragma unroll
    for (int sb = 0; sb < 2; ++sb)
#pragma unroll
      for (int kf = 0; kf < 4; ++kf)
        kfr[sb][kf] = *reinterpret_cast<const bf16x8*>(Kp + sb * 2048 + kf * 512);

    // ---- QK^T (kfr dies here) ----
    f32x16 sacc[2];
#pragma unroll
    for (int sb = 0; sb < 2; ++sb)
#pragma unroll
      for (int r = 0; r < 16; ++r) sacc[sb][r] = 0.f;
    __builtin_amdgcn_s_setprio(1);
#pragma unroll
    for (int sb = 0; sb < 2; ++sb)
#pragma unroll
      for (int kf = 0; kf < 4; ++kf)
        sacc[sb] = __builtin_amdgcn_mfma_f32_32x32x16_bf16(kfr[sb][kf], qf[kf], sacc[sb], 0, 0, 0);
    __builtin_amdgcn_s_setprio(0);

    // ---- V issued now: round-trip hides under exp + pack ----
    bf16x8 vf[2][2][2];  // [df][sb][ks]
#pragma unroll
    for (int df = 0; df < 2; ++df)
#pragma unroll
      for (int sb = 0; sb < 2; ++sb)
#pragma unroll
        for (int ks = 0; ks < 2; ++ks)
          vf[df][sb][ks] =
              *reinterpret_cast<const bf16x8*>(Vp + (size_t)(df * 4 + sb * 2 + ks) * 512);

    // ---- static-max softmax: P = 2^s straight from MFMA output ----
    float a0 = 0.f, a1 = 0.f, a2 = 0.f, a3 = 0.f;
#pragma unroll
    for (int sb = 0; sb < 2; ++sb)
#pragma unroll
      for (int r = 0; r < 16; r += 4) {
        float e0 = exp2r(sacc[sb][r]);
        float e1 = exp2r(sacc[sb][r + 1]);
        float e2 = exp2r(sacc[sb][r + 2]);
        float e3 = exp2r(sacc[sb][r + 3]);
        sacc[sb][r] = e0; sacc[sb][r + 1] = e1; sacc[sb][r + 2] = e2; sacc[sb][r + 3] = e3;
        a0 += e0; a1 += e1; a2 += e2; a3 += e3;
      }
    lp += (a0 + a1) + (a2 + a3);

    // ---- pack P to B-frag layout via v_permlane32_swap_b32 ----
    bf16x8 pf[2][2];  // [sb][ks]
#pragma unroll
    for (int sb = 0; sb < 2; ++sb) {
      u32 pw[8];
#pragma unroll
      for (int r2 = 0; r2 < 8; ++r2) {
        u32 o;
        asm("v_cvt_pk_bf16_f32 %0, %1, %2"
            : "=v"(o)
            : "v"(sacc[sb][2 * r2]), "v"(sacc[sb][2 * r2 + 1]));
        pw[r2] = o;
      }
      u32 fw[2][4];
#pragma unroll
      for (int pp = 0; pp < 4; ++pp) {
        int ks = pp >> 1, o = pp & 1;
        u32 a = pw[ks * 4 + o], bq = pw[ks * 4 + o + 2];
        asm("v_permlane32_swap_b32 %0, %1" : "+v"(a), "+v"(bq));
        fw[ks][o] = a;
        fw[ks][o + 2] = bq;
      }
#pragma unroll
      for (int ks = 0; ks < 2; ++ks) {
        i32x4 iv = {(int)fw[ks][0], (int)fw[ks][1], (int)fw[ks][2], (int)fw[ks][3]};
        pf[sb][ks] = __builtin_bit_cast(bf16x8, iv);
      }
    }

    // ---- O^T += Vt * P^T ----
    __builtin_amdgcn_s_setprio(1);
#pragma unroll
    for (int df = 0; df < 2; ++df)
#pragma unroll
      for (int sb = 0; sb < 2; ++sb)
#pragma unroll
        for (int ks = 0; ks < 2; ++ks)
          oacc[df] =
              __builtin_amdgcn_mfma_f32_32x32x16_bf16(vf[df][sb][ks], pf[sb][ks], oacc[df], 0, 0, 0);
    __builtin_amdgcn_s_setprio(0);
  }

  // ---- sequential split merge (pure sums): spl 1..3 publish; spl 0 adds ----
  lp += __shfl_xor(lp, 32);

  for (int src = 1; src < 4; ++src) {
    if (spl == src) {
      float* cb = &cmb[qsub][l31][0];
#pragma unroll
      for (int df = 0; df < 2; ++df)
#pragma unroll
        for (int r = 0; r < 16; ++r) {
          int d = df * 32 + (r & 3) + 8 * (r >> 2) + 4 * hi;
          cb[d] = oacc[df][r];
        }
      if (hi == 0) cb[64] = lp;
    }
    __syncthreads();
    if (spl == 0) {
      const float* cb = &cmb[qsub][l31][0];
      lp += cb[64];
#pragma unroll
      for (int df = 0; df < 2; ++df)
#pragma unroll
        for (int r = 0; r < 16; ++r) {
          int d = df * 32 + (r & 3) + 8 * (r >> 2) + 4 * hi;
          oacc[df][r] += cb[d];
        }
    }
    __syncthreads();  // WAR: publisher slot reused next round
  }

  if (spl == 0) {  // normalize + stage final bf16 O for coalesced store
    float linv = 1.0f / lp;
#pragma unroll
    for (int df = 0; df < 2; ++df)
#pragma unroll
      for (int r = 0; r < 16; ++r) {
        int d = df * 32 + (r & 3) + 8 * (r >> 2) + 4 * hi;
        ot[qsub][l31][d] = f2bf(oacc[df][r] * linv);
      }
  }
  __syncthreads();
  if (spl == 0) {
    int tr = lane >> 1, dblk = (lane & 1) * 32;
    u16* gdst = Oa + ((size_t)(b * Tt + t0 + tr)) * Dd + h * HD + dblk;
#pragma unroll
    for (int c = 0; c < 4; ++c) {
      ushort8v vv = *reinterpret_cast<const ushort8v*>(&ot[qsub][tr][dblk + c * 8]);
      *reinterpret_cast<ushort8v*>(gdst + c * 8) = vv;
    }
  }
}

// ---------------------------------------------------------------- launch
extern "C" void kernel_launch(void* const* d_in, const int* in_sizes, int n_in, void* d_out,
                              int out_size, void* d_ws, size_t ws_size, hipStream_t stream) {
  (void)in_sizes; (void)n_in; (void)out_size; (void)ws_size;
  const float* x = (const float*)d_in[0];
  const float* cosT = (const float*)d_in[1];
  const float* sinT = (const float*)d_in[2];
  const float* Wq = (const float*)d_in[3];
  const float* Wkv = (const float*)d_in[4];
  const float* Wo = (const float*)d_in[5];

  char* p = (char*)d_ws;
  u16* xb = (u16*)p;   p += (size_t)4096 * 1024 * 2;
  u16* wqkv = (u16*)p; p += (size_t)1536 * 1024 * 2;
  u16* wob = (u16*)p;  p += (size_t)1024 * 1024 * 2;
  u16* Pbuf = (u16*)p; p += (size_t)4096 * 1536 * 2;
  u16* Qb = (u16*)p;   p += (size_t)Bb * QH * Tt * HD * 2;
  u16* Kbuf = (u16*)p; p += (size_t)Bb * KVH * Tt * HD * 2;
  u16* Vfb = (u16*)p;  p += (size_t)Bb * KVH * HD * Tt * 2;
  u16* Ob = Pbuf;  // Pbuf dead after rope_vt

  cvt_all<<<6656, 256, 0, stream>>>(x, Wq, Wkv, Wo, xb, wqkv, wob);
  gemm_bt<false, 4><<<dim3(12, 32), 256, 0, stream>>>(xb, wqkv, Pbuf, 4096, 1536, 1024);
  rope_vt<<<10496, 256, 0, stream>>>(Pbuf, cosT, sinT, Qb, Kbuf, Vfb);
  attn_fwd9<<<1024, 512, 0, stream>>>(Qb, Kbuf, Vfb, Ob);
  gemm_bt<true, 2><<<dim3(16, 32), 256, 0, stream>>>(Ob, wob, d_out, 4096, 1024, 1024);
}

// Round 11
// 99.863 us; speedup vs baseline: 1.8107x; 1.0757x over previous
//
#include <hip/hip_runtime.h>

// GQA attention fused pipeline for MI355X (gfx950).
// cvt(fused) -> GEMM(QKV, reg-staged prefetch) -> fused RoPE/scatter +
// V-transpose (fragment-major) -> flash attention (LDS-shared K/V via
// global_load_lds, 4 heads x 2 splits per block, static-max softmax)
// -> GEMM(out, BN=64).

typedef __bf16 bf16x8 __attribute__((ext_vector_type(8)));
typedef float f32x4 __attribute__((ext_vector_type(4)));
typedef float f32x16 __attribute__((ext_vector_type(16)));
typedef int i32x4 __attribute__((ext_vector_type(4)));
typedef unsigned short ushort4v __attribute__((ext_vector_type(4)));
typedef unsigned short ushort8v __attribute__((ext_vector_type(8)));
typedef unsigned short u16;
typedef unsigned int u32;

#define DEVINL __device__ __forceinline__

DEVINL float bf2f(u16 u) {
  unsigned int x = ((unsigned int)u) << 16;
  return __builtin_bit_cast(float, x);
}
DEVINL u16 f2bf(float f) {  // RTNE
  unsigned int x = __builtin_bit_cast(unsigned int, f);
  x += 0x7fffu + ((x >> 16) & 1u);
  return (u16)(x >> 16);
}
// raw 2^x — single v_exp_f32
DEVINL float exp2r(float x) {
  float r;
  asm("v_exp_f32 %0, %1" : "=v"(r) : "v"(x));
  return r;
}
// async global->LDS, 16B/lane; LDS dest = wave-uniform base + lane*16
DEVINL void gld16(const u16* g, u16* l) {
  __builtin_amdgcn_global_load_lds(
      (const __attribute__((address_space(1))) void*)g,
      (__attribute__((address_space(3))) void*)l, 16, 0, 0);
}

constexpr int Bb = 2, Tt = 2048, Dd = 1024, QH = 16, KVH = 4, HD = 64;
constexpr float SCALE_L2E = 0.125f * 1.44269504088896340736f;
constexpr int KVSZ = 131072;  // per-(b,kvh) fragment-major K/V extent (elems)

// ---------------------------------------------------------------- fused convert
__global__ void cvt_all(const float* __restrict__ x, const float* __restrict__ Wq,
                        const float* __restrict__ Wkv, const float* __restrict__ Wo,
                        u16* __restrict__ xb, u16* __restrict__ wqkv,
                        u16* __restrict__ wob) {
  int i = blockIdx.x * 256 + threadIdx.x;  // grid covers 1,703,936 float4s exactly
  const float* src;
  u16* dst;
  if (i < 1048576) {
    src = x; dst = xb;
  } else if (i < 1310720) {
    src = Wq - (size_t)1048576 * 4; dst = wqkv - (size_t)1048576 * 4;
  } else if (i < 1441792) {
    src = Wkv - (size_t)1310720 * 4; dst = wqkv + (size_t)1024 * 1024 - (size_t)1310720 * 4;
  } else {
    src = Wo - (size_t)1441792 * 4; dst = wob - (size_t)1441792 * 4;
  }
  float4 v = reinterpret_cast<const float4*>(src)[i];
  ushort4v o = {f2bf(v.x), f2bf(v.y), f2bf(v.z), f2bf(v.w)};
  *reinterpret_cast<ushort4v*>(dst + (size_t)i * 4) = o;
}

// ---------------------------------------------------------------- GEMM C = A(M,K) @ B(N,K)^T
// reg-staged prefetch; BM=128, BN=BNF*32. 4 waves, XOR-swizzled LDS chunks.
template <bool OUT_F32, int BNF>
__global__ __launch_bounds__(256) void gemm_bt(const u16* __restrict__ A,
                                               const u16* __restrict__ Bw,
                                               void* __restrict__ Cout, int M, int N, int K) {
  __shared__ alignas(16) u16 lA[128 * 64];
  __shared__ alignas(16) u16 lB[BNF * 32 * 64];
  const int tid = threadIdx.x;
  const int w = tid >> 6, lane = tid & 63;
  const int r16 = lane & 15, g4 = lane >> 4;
  const int row0 = blockIdx.y * 128, col0 = blockIdx.x * (BNF * 32);
  const int sr = tid >> 3, sc = tid & 7;
  const int NT = K >> 6;

  bf16x8 ra[4], rb[BNF];
  f32x4 acc[4][BNF];
#pragma unroll
  for (int i = 0; i < 4; ++i)
#pragma unroll
    for (int j = 0; j < BNF; ++j) acc[i][j] = f32x4{0.f, 0.f, 0.f, 0.f};

  const int wm = (w >> 1) * 64, wn = (w & 1) * (BNF * 8);

#pragma unroll
  for (int i = 0; i < 4; ++i) {
    int r = i * 32 + sr;
    ra[i] = *reinterpret_cast<const bf16x8*>(A + (size_t)(row0 + r) * K + sc * 8);
  }
#pragma unroll
  for (int i = 0; i < BNF; ++i) {
    int r = i * 32 + sr;
    rb[i] = *reinterpret_cast<const bf16x8*>(Bw + (size_t)(col0 + r) * K + sc * 8);
  }

  for (int kt = 0; kt < NT; ++kt) {
    __syncthreads();
#pragma unroll
    for (int i = 0; i < 4; ++i) {
      int r = i * 32 + sr;
      int c = (sc ^ (r & 7)) * 8;
      *reinterpret_cast<bf16x8*>(&lA[r * 64 + c]) = ra[i];
    }
#pragma unroll
    for (int i = 0; i < BNF; ++i) {
      int r = i * 32 + sr;
      int c = (sc ^ (r & 7)) * 8;
      *reinterpret_cast<bf16x8*>(&lB[r * 64 + c]) = rb[i];
    }
    __syncthreads();
    if (kt + 1 < NT) {
      int k0 = (kt + 1) << 6;
#pragma unroll
      for (int i = 0; i < 4; ++i) {
        int r = i * 32 + sr;
        ra[i] = *reinterpret_cast<const bf16x8*>(A + (size_t)(row0 + r) * K + k0 + sc * 8);
      }
#pragma unroll
      for (int i = 0; i < BNF; ++i) {
        int r = i * 32 + sr;
        rb[i] = *reinterpret_cast<const bf16x8*>(Bw + (size_t)(col0 + r) * K + k0 + sc * 8);
      }
    }
#pragma unroll
    for (int kk = 0; kk < 2; ++kk) {
      bf16x8 af[4], bfr[BNF];
#pragma unroll
      for (int mf = 0; mf < 4; ++mf) {
        int r = wm + mf * 16 + r16;
        int c = ((kk * 4 + g4) ^ (r & 7)) * 8;
        af[mf] = *reinterpret_cast<const bf16x8*>(&lA[r * 64 + c]);
      }
#pragma unroll
      for (int nf = 0; nf < BNF; ++nf) {
        int r = wn * 2 + nf * 16 + r16;
        int c = ((kk * 4 + g4) ^ (r & 7)) * 8;
        bfr[nf] = *reinterpret_cast<const bf16x8*>(&lB[r * 64 + c]);
      }
#pragma unroll
      for (int mf = 0; mf < 4; ++mf)
#pragma unroll
        for (int nf = 0; nf < BNF; ++nf)
          acc[mf][nf] =
              __builtin_amdgcn_mfma_f32_16x16x32_bf16(af[mf], bfr[nf], acc[mf][nf], 0, 0, 0);
    }
  }

#pragma unroll
  for (int mf = 0; mf < 4; ++mf)
#pragma unroll
    for (int nf = 0; nf < BNF; ++nf)
#pragma unroll
      for (int r = 0; r < 4; ++r) {
        size_t row = (size_t)(row0 + wm + mf * 16 + g4 * 4 + r);
        size_t col = (size_t)(col0 + wn * 2 + nf * 16 + r16);
        float v = acc[mf][nf][r];
        if (OUT_F32)
          reinterpret_cast<float*>(Cout)[row * N + col] = v;
        else
          reinterpret_cast<u16*>(Cout)[row * N + col] = f2bf(v);
      }
}

// ---------------------------------------------------------------- fused RoPE/scatter + V-transpose
__global__ void rope_vt(const u16* __restrict__ P, const float* __restrict__ cosT,
                        const float* __restrict__ sinT, u16* __restrict__ Q,
                        u16* __restrict__ Kc, u16* __restrict__ Vf) {
  __shared__ u16 tile[64][72];
  const int bid = blockIdx.x;
  const int tid = threadIdx.x;
  if (bid < 10240) {
    int idx = bid * 256 + tid;
    int row = idx / 640, p = idx - row * 640;
    int b = row >> 11, t = row & 2047;
    int n, d;
    u16* outp;
    float scl;
    if (p < 512) {
      n = p * 2;
      int h = n >> 6;
      d = n & 63;
      outp = Q + ((size_t)(b * QH + h) * Tt + t) * HD + d;
      scl = SCALE_L2E;
    } else {
      int r2 = p - 512;
      int kvh = r2 >> 5, dp = r2 & 31;
      d = dp * 2;
      n = 1024 + kvh * 128 + d;
      int bh = b * KVH + kvh;
      int kf = d >> 4, h8 = (d >> 3) & 1, j = d & 7;  // j even
      outp = Kc + (size_t)bh * KVSZ + ((t >> 5) * 4 + kf) * 512 + (h8 * 32 + (t & 31)) * 8 + j;
      scl = 1.0f;
    }
    unsigned int pv = *reinterpret_cast<const unsigned int*>(P + (size_t)row * 1536 + n);
    float v0 = bf2f((u16)(pv & 0xffffu)), v1 = bf2f((u16)(pv >> 16));
    float c = cosT[t * HD + d], s = sinT[t * HD + d];
    float o0 = (v0 * c - v1 * s) * scl;
    float o1 = (v1 * c + v0 * s) * scl;
    unsigned int ob = (unsigned int)f2bf(o0) | ((unsigned int)f2bf(o1) << 16);
    *reinterpret_cast<unsigned int*>(outp) = ob;
  } else {
    int rem = bid - 10240;
    int bh = rem >> 5, tt = rem & 31;
    int b = bh >> 2, kvh = bh & 3;
    int t0 = tt * 64;
    int colbase = 1024 + kvh * 128 + 64;
#pragma unroll
    for (int j = 0; j < 4; ++j) {
      int rr = j * 16 + (tid >> 4);
      int cc = (tid & 15) * 4;
      *reinterpret_cast<uint2*>(&tile[rr][cc]) =
          *reinterpret_cast<const uint2*>(P + (size_t)(b * Tt + t0 + rr) * 1536 + colbase + cc);
    }
    __syncthreads();
#pragma unroll
    for (int kk = 0; kk < 2; ++kk) {
      int CH = kk * 256 + tid;
      int df = CH >> 8, sbks = (CH >> 6) & 3, h8 = (CH >> 5) & 1, l = CH & 31;
      int d = df * 32 + l;
      int c = (sbks >> 1) * 4 + (sbks & 1) * 2 + h8;
      ushort8v v;
#pragma unroll
      for (int j = 0; j < 8; ++j) v[j] = tile[c * 8 + j][d];
      u16* dst = Vf + (size_t)bh * KVSZ + (((t0 >> 6) * 2 + df) * 4 + sbks) * 512 +
                 (h8 * 32 + l) * 8;
      *reinterpret_cast<ushort8v*>(dst) = v;
    }
  }
}

// ---------------------------------------------------------------- flash attention v10
// 8 waves = {head g 0..3} x {split spl 0,1}; 32 q-rows/block; grid 512 = 2/CU.
// K/V staged to LDS once per block per 64-key step via global_load_lds (the
// fragment-major tile is one contiguous 8KB block -> linear lane*16 dest is
// exact). 4 head-waves share each split's K/V from LDS: global K/V traffic
// drops 4x vs r9. Double-buffered, one barrier/step (T3 2-phase recipe).
// Static-max softmax + permlane pack unchanged. 2-way split merge via LDS.
__global__ __launch_bounds__(512, 4) void attn_fwd10(const u16* __restrict__ Q,
                                                     const u16* __restrict__ Kf,
                                                     const u16* __restrict__ Vf,
                                                     u16* __restrict__ Oa) {
  // arena: [0,16K) K dbuf{2}x split{2} 4096 elems each; [16K,32K) V same.
  // after main loop, bytes [0,33.8K) alias the merge buffer, [34816,...) O-stage.
  __shared__ alignas(16) u16 arena[32768];
  const int tid = threadIdx.x;
  const int w = tid >> 6, lane = tid & 63;
  const int g = w & 3, spl = w >> 2;
  const int l31 = lane & 31, hi = lane >> 5;

  const int fid = blockIdx.x;
  const int xcd = fid & 7, idx = fid >> 3;  // xcd == (b,kvh)
  const int b = xcd >> 2, kvh = xcd & 3;
  const int h = kvh * 4 + g;
  const int t0 = idx * 32;
  const size_t bh = (size_t)(b * KVH + kvh);

  // staging duty: region rg = w&3 (0:K-s0 1:K-s1 2:V-s0 3:V-s1), half = spl
  const int rg = w & 3;
  const int sv = rg & 1, isV = rg >> 1;
  const u16* gsrc = (isV ? Vf : Kf) + bh * KVSZ + sv * 65536 + spl * 2048 + lane * 8;
  const int ldst0 = isV * 16384 + sv * 4096 + spl * 2048;  // elems; +cur*8192 +i*512

  const u16* Qh = Q + ((size_t)(b * QH + h) * Tt + t0 + l31) * HD + hi * 8;
  bf16x8 qf[4];
#pragma unroll
  for (int kf = 0; kf < 4; ++kf)
    qf[kf] = *reinterpret_cast<const bf16x8*>(Qh + kf * 16);

  f32x16 oacc[2];
#pragma unroll
  for (int df = 0; df < 2; ++df)
#pragma unroll
    for (int r = 0; r < 16; ++r) oacc[df][r] = 0.f;
  float lp = 0.f;

  // prologue: stage step 0 into buf 0, wait (barrier drains vmcnt)
#pragma unroll
  for (int i = 0; i < 4; ++i) gld16(gsrc + i * 512, &arena[ldst0 + i * 512]);
  __syncthreads();

  int cur = 0;
  for (int it = 0; it < 16; ++it) {
    if (it < 15) {  // stage next step into the other buffer (in flight across compute)
      const u16* gs = gsrc + (it + 1) * 4096;
      u16* ld = &arena[ldst0 + (cur ^ 1) * 8192];
#pragma unroll
      for (int i = 0; i < 4; ++i) gld16(gs + i * 512, ld + i * 512);
    }
    const int ktb = cur * 8192 + spl * 4096;
    const int vtb = 16384 + cur * 8192 + spl * 4096;

    // ---- QK^T from LDS fragments ----
    f32x16 sacc[2];
#pragma unroll
    for (int sb = 0; sb < 2; ++sb) {
      bf16x8 kfr[4];
#pragma unroll
      for (int kf = 0; kf < 4; ++kf)
        kfr[kf] = *reinterpret_cast<const bf16x8*>(&arena[ktb + sb * 2048 + kf * 512 + lane * 8]);
#pragma unroll
      for (int r = 0; r < 16; ++r) sacc[sb][r] = 0.f;
      __builtin_amdgcn_s_setprio(1);
#pragma unroll
      for (int kf = 0; kf < 4; ++kf)
        sacc[sb] = __builtin_amdgcn_mfma_f32_32x32x16_bf16(kfr[kf], qf[kf], sacc[sb], 0, 0, 0);
      __builtin_amdgcn_s_setprio(0);
    }

    // ---- static-max softmax: P = 2^s ----
    float a0 = 0.f, a1 = 0.f, a2 = 0.f, a3 = 0.f;
#pragma unroll
    for (int sb = 0; sb < 2; ++sb)
#pragma unroll
      for (int r = 0; r < 16; r += 4) {
        float e0 = exp2r(sacc[sb][r]);
        float e1 = exp2r(sacc[sb][r + 1]);
        float e2 = exp2r(sacc[sb][r + 2]);
        float e3 = exp2r(sacc[sb][r + 3]);
        sacc[sb][r] = e0; sacc[sb][r + 1] = e1; sacc[sb][r + 2] = e2; sacc[sb][r + 3] = e3;
        a0 += e0; a1 += e1; a2 += e2; a3 += e3;
      }
    lp += (a0 + a1) + (a2 + a3);

    // ---- pack P to B-frag layout via v_permlane32_swap_b32 ----
    bf16x8 pf[2][2];
#pragma unroll
    for (int sb = 0; sb < 2; ++sb) {
      u32 pw[8];
#pragma unroll
      for (int r2 = 0; r2 < 8; ++r2) {
        u32 o;
        asm("v_cvt_pk_bf16_f32 %0, %1, %2"
            : "=v"(o)
            : "v"(sacc[sb][2 * r2]), "v"(sacc[sb][2 * r2 + 1]));
        pw[r2] = o;
      }
      u32 fw[2][4];
#pragma unroll
      for (int pp = 0; pp < 4; ++pp) {
        int ks = pp >> 1, o = pp & 1;
        u32 a = pw[ks * 4 + o], bq = pw[ks * 4 + o + 2];
        asm("v_permlane32_swap_b32 %0, %1" : "+v"(a), "+v"(bq));
        fw[ks][o] = a;
        fw[ks][o + 2] = bq;
      }
#pragma unroll
      for (int ks = 0; ks < 2; ++ks) {
        i32x4 iv = {(int)fw[ks][0], (int)fw[ks][1], (int)fw[ks][2], (int)fw[ks][3]};
        pf[sb][ks] = __builtin_bit_cast(bf16x8, iv);
      }
    }

    // ---- PV from LDS V fragments ----
    __builtin_amdgcn_s_setprio(1);
#pragma unroll
    for (int df = 0; df < 2; ++df)
#pragma unroll
      for (int sb = 0; sb < 2; ++sb)
#pragma unroll
        for (int ks = 0; ks < 2; ++ks) {
          bf16x8 vfr = *reinterpret_cast<const bf16x8*>(
              &arena[vtb + (df * 4 + sb * 2 + ks) * 512 + lane * 8]);
          oacc[df] = __builtin_amdgcn_mfma_f32_32x32x16_bf16(vfr, pf[sb][ks], oacc[df], 0, 0, 0);
        }
    __builtin_amdgcn_s_setprio(0);

    __syncthreads();  // drains stage loads (vmcnt 0) + protects buffer swap
    cur ^= 1;
  }

  // ---- split merge (2 ways): spl1 publishes, spl0 adds; then store ----
  lp += __shfl_xor(lp, 32);
  float* cb = reinterpret_cast<float*>(arena) + ((size_t)g * 32 + l31) * 66;
  if (spl == 1) {
#pragma unroll
    for (int df = 0; df < 2; ++df)
#pragma unroll
      for (int r = 0; r < 16; ++r) {
        int d = df * 32 + (r & 3) + 8 * (r >> 2) + 4 * hi;
        cb[d] = oacc[df][r];
      }
    if (hi == 0) cb[64] = lp;
  }
  __syncthreads();
  if (spl == 0) {
    lp += cb[64];
    float linv = 1.0f / lp;
    u16* otg = arena + 17408 + g * 2304;  // 32 rows x 72, aliased past cmb region
#pragma unroll
    for (int df = 0; df < 2; ++df)
#pragma unroll
      for (int r = 0; r < 16; ++r) {
        int d = df * 32 + (r & 3) + 8 * (r >> 2) + 4 * hi;
        otg[l31 * 72 + d] = f2bf((oacc[df][r] + cb[d]) * linv);
      }
  }
  __syncthreads();
  if (spl == 0) {
    const u16* otg = arena + 17408 + g * 2304;
    int tr = lane >> 1, dblk = (lane & 1) * 32;
    u16* gdst = Oa + ((size_t)(b * Tt + t0 + tr)) * Dd + h * HD + dblk;
#pragma unroll
    for (int c = 0; c < 4; ++c) {
      ushort8v vv = *reinterpret_cast<const ushort8v*>(&otg[tr * 72 + dblk + c * 8]);
      *reinterpret_cast<ushort8v*>(gdst + c * 8) = vv;
    }
  }
}

// ---------------------------------------------------------------- launch
extern "C" void kernel_launch(void* const* d_in, const int* in_sizes, int n_in, void* d_out,
                              int out_size, void* d_ws, size_t ws_size, hipStream_t stream) {
  (void)in_sizes; (void)n_in; (void)out_size; (void)ws_size;
  const float* x = (const float*)d_in[0];
  const float* cosT = (const float*)d_in[1];
  const float* sinT = (const float*)d_in[2];
  const float* Wq = (const float*)d_in[3];
  const float* Wkv = (const float*)d_in[4];
  const float* Wo = (const float*)d_in[5];

  char* p = (char*)d_ws;
  u16* xb = (u16*)p;   p += (size_t)4096 * 1024 * 2;
  u16* wqkv = (u16*)p; p += (size_t)1536 * 1024 * 2;
  u16* wob = (u16*)p;  p += (size_t)1024 * 1024 * 2;
  u16* Pbuf = (u16*)p; p += (size_t)4096 * 1536 * 2;
  u16* Qb = (u16*)p;   p += (size_t)Bb * QH * Tt * HD * 2;
  u16* Kbuf = (u16*)p; p += (size_t)Bb * KVH * Tt * HD * 2;
  u16* Vfb = (u16*)p;  p += (size_t)Bb * KVH * HD * Tt * 2;
  u16* Ob = Pbuf;  // Pbuf dead after rope_vt

  cvt_all<<<6656, 256, 0, stream>>>(x, Wq, Wkv, Wo, xb, wqkv, wob);
  gemm_bt<false, 4><<<dim3(12, 32), 256, 0, stream>>>(xb, wqkv, Pbuf, 4096, 1536, 1024);
  rope_vt<<<10496, 256, 0, stream>>>(Pbuf, cosT, sinT, Qb, Kbuf, Vfb);
  attn_fwd10<<<512, 512, 0, stream>>>(Qb, Kbuf, Vfb, Ob);
  gemm_bt<true, 2><<<dim3(16, 32), 256, 0, stream>>>(Ob, wob, d_out, 4096, 1024, 1024);
}

// Round 12
// 99.124 us; speedup vs baseline: 1.8242x; 1.0075x over previous
//
#include <hip/hip_runtime.h>

// GQA attention fused pipeline for MI355X (gfx950).
// cvt(fused) -> GEMM(QKV, reg-staged, BN=64) -> fused RoPE/scatter +
// V-transpose (fragment-major) -> flash attention (LDS-shared K/V,
// half-tile pipelined QK/SM/PV interleave, static-max softmax)
// -> GEMM(out, BN=64).

typedef __bf16 bf16x8 __attribute__((ext_vector_type(8)));
typedef float f32x4 __attribute__((ext_vector_type(4)));
typedef float f32x16 __attribute__((ext_vector_type(16)));
typedef int i32x4 __attribute__((ext_vector_type(4)));
typedef unsigned short ushort4v __attribute__((ext_vector_type(4)));
typedef unsigned short ushort8v __attribute__((ext_vector_type(8)));
typedef unsigned short u16;
typedef unsigned int u32;

#define DEVINL __device__ __forceinline__

DEVINL float bf2f(u16 u) {
  unsigned int x = ((unsigned int)u) << 16;
  return __builtin_bit_cast(float, x);
}
DEVINL u16 f2bf(float f) {  // RTNE
  unsigned int x = __builtin_bit_cast(unsigned int, f);
  x += 0x7fffu + ((x >> 16) & 1u);
  return (u16)(x >> 16);
}
// raw 2^x — single v_exp_f32
DEVINL float exp2r(float x) {
  float r;
  asm("v_exp_f32 %0, %1" : "=v"(r) : "v"(x));
  return r;
}
// async global->LDS, 16B/lane; LDS dest = wave-uniform base + lane*16
DEVINL void gld16(const u16* g, u16* l) {
  __builtin_amdgcn_global_load_lds(
      (const __attribute__((address_space(1))) void*)g,
      (__attribute__((address_space(3))) void*)l, 16, 0, 0);
}

constexpr int Bb = 2, Tt = 2048, Dd = 1024, QH = 16, KVH = 4, HD = 64;
constexpr float SCALE_L2E = 0.125f * 1.44269504088896340736f;
constexpr int KVSZ = 131072;  // per-(b,kvh) fragment-major K/V extent (elems)

// ---------------------------------------------------------------- fused convert
__global__ void cvt_all(const float* __restrict__ x, const float* __restrict__ Wq,
                        const float* __restrict__ Wkv, const float* __restrict__ Wo,
                        u16* __restrict__ xb, u16* __restrict__ wqkv,
                        u16* __restrict__ wob) {
  int i = blockIdx.x * 256 + threadIdx.x;  // grid covers 1,703,936 float4s exactly
  const float* src;
  u16* dst;
  if (i < 1048576) {
    src = x; dst = xb;
  } else if (i < 1310720) {
    src = Wq - (size_t)1048576 * 4; dst = wqkv - (size_t)1048576 * 4;
  } else if (i < 1441792) {
    src = Wkv - (size_t)1310720 * 4; dst = wqkv + (size_t)1024 * 1024 - (size_t)1310720 * 4;
  } else {
    src = Wo - (size_t)1441792 * 4; dst = wob - (size_t)1441792 * 4;
  }
  float4 v = reinterpret_cast<const float4*>(src)[i];
  ushort4v o = {f2bf(v.x), f2bf(v.y), f2bf(v.z), f2bf(v.w)};
  *reinterpret_cast<ushort4v*>(dst + (size_t)i * 4) = o;
}

// ---------------------------------------------------------------- GEMM C = A(M,K) @ B(N,K)^T
// reg-staged prefetch; BM=128, BN=BNF*32. 4 waves, XOR-swizzled LDS chunks.
template <bool OUT_F32, int BNF>
__global__ __launch_bounds__(256) void gemm_bt(const u16* __restrict__ A,
                                               const u16* __restrict__ Bw,
                                               void* __restrict__ Cout, int M, int N, int K) {
  __shared__ alignas(16) u16 lA[128 * 64];
  __shared__ alignas(16) u16 lB[BNF * 32 * 64];
  const int tid = threadIdx.x;
  const int w = tid >> 6, lane = tid & 63;
  const int r16 = lane & 15, g4 = lane >> 4;
  const int row0 = blockIdx.y * 128, col0 = blockIdx.x * (BNF * 32);
  const int sr = tid >> 3, sc = tid & 7;
  const int NT = K >> 6;

  bf16x8 ra[4], rb[BNF];
  f32x4 acc[4][BNF];
#pragma unroll
  for (int i = 0; i < 4; ++i)
#pragma unroll
    for (int j = 0; j < BNF; ++j) acc[i][j] = f32x4{0.f, 0.f, 0.f, 0.f};

  const int wm = (w >> 1) * 64, wn = (w & 1) * (BNF * 8);

#pragma unroll
  for (int i = 0; i < 4; ++i) {
    int r = i * 32 + sr;
    ra[i] = *reinterpret_cast<const bf16x8*>(A + (size_t)(row0 + r) * K + sc * 8);
  }
#pragma unroll
  for (int i = 0; i < BNF; ++i) {
    int r = i * 32 + sr;
    rb[i] = *reinterpret_cast<const bf16x8*>(Bw + (size_t)(col0 + r) * K + sc * 8);
  }

  for (int kt = 0; kt < NT; ++kt) {
    __syncthreads();
#pragma unroll
    for (int i = 0; i < 4; ++i) {
      int r = i * 32 + sr;
      int c = (sc ^ (r & 7)) * 8;
      *reinterpret_cast<bf16x8*>(&lA[r * 64 + c]) = ra[i];
    }
#pragma unroll
    for (int i = 0; i < BNF; ++i) {
      int r = i * 32 + sr;
      int c = (sc ^ (r & 7)) * 8;
      *reinterpret_cast<bf16x8*>(&lB[r * 64 + c]) = rb[i];
    }
    __syncthreads();
    if (kt + 1 < NT) {
      int k0 = (kt + 1) << 6;
#pragma unroll
      for (int i = 0; i < 4; ++i) {
        int r = i * 32 + sr;
        ra[i] = *reinterpret_cast<const bf16x8*>(A + (size_t)(row0 + r) * K + k0 + sc * 8);
      }
#pragma unroll
      for (int i = 0; i < BNF; ++i) {
        int r = i * 32 + sr;
        rb[i] = *reinterpret_cast<const bf16x8*>(Bw + (size_t)(col0 + r) * K + k0 + sc * 8);
      }
    }
#pragma unroll
    for (int kk = 0; kk < 2; ++kk) {
      bf16x8 af[4], bfr[BNF];
#pragma unroll
      for (int mf = 0; mf < 4; ++mf) {
        int r = wm + mf * 16 + r16;
        int c = ((kk * 4 + g4) ^ (r & 7)) * 8;
        af[mf] = *reinterpret_cast<const bf16x8*>(&lA[r * 64 + c]);
      }
#pragma unroll
      for (int nf = 0; nf < BNF; ++nf) {
        int r = wn * 2 + nf * 16 + r16;
        int c = ((kk * 4 + g4) ^ (r & 7)) * 8;
        bfr[nf] = *reinterpret_cast<const bf16x8*>(&lB[r * 64 + c]);
      }
#pragma unroll
      for (int mf = 0; mf < 4; ++mf)
#pragma unroll
        for (int nf = 0; nf < BNF; ++nf)
          acc[mf][nf] =
              __builtin_amdgcn_mfma_f32_16x16x32_bf16(af[mf], bfr[nf], acc[mf][nf], 0, 0, 0);
    }
  }

#pragma unroll
  for (int mf = 0; mf < 4; ++mf)
#pragma unroll
    for (int nf = 0; nf < BNF; ++nf)
#pragma unroll
      for (int r = 0; r < 4; ++r) {
        size_t row = (size_t)(row0 + wm + mf * 16 + g4 * 4 + r);
        size_t col = (size_t)(col0 + wn * 2 + nf * 16 + r16);
        float v = acc[mf][nf][r];
        if (OUT_F32)
          reinterpret_cast<float*>(Cout)[row * N + col] = v;
        else
          reinterpret_cast<u16*>(Cout)[row * N + col] = f2bf(v);
      }
}

// ---------------------------------------------------------------- fused RoPE/scatter + V-transpose
__global__ void rope_vt(const u16* __restrict__ P, const float* __restrict__ cosT,
                        const float* __restrict__ sinT, u16* __restrict__ Q,
                        u16* __restrict__ Kc, u16* __restrict__ Vf) {
  __shared__ u16 tile[64][72];
  const int bid = blockIdx.x;
  const int tid = threadIdx.x;
  if (bid < 10240) {
    int idx = bid * 256 + tid;
    int row = idx / 640, p = idx - row * 640;
    int b = row >> 11, t = row & 2047;
    int n, d;
    u16* outp;
    float scl;
    if (p < 512) {
      n = p * 2;
      int h = n >> 6;
      d = n & 63;
      outp = Q + ((size_t)(b * QH + h) * Tt + t) * HD + d;
      scl = SCALE_L2E;
    } else {
      int r2 = p - 512;
      int kvh = r2 >> 5, dp = r2 & 31;
      d = dp * 2;
      n = 1024 + kvh * 128 + d;
      int bh = b * KVH + kvh;
      int kf = d >> 4, h8 = (d >> 3) & 1, j = d & 7;  // j even
      outp = Kc + (size_t)bh * KVSZ + ((t >> 5) * 4 + kf) * 512 + (h8 * 32 + (t & 31)) * 8 + j;
      scl = 1.0f;
    }
    unsigned int pv = *reinterpret_cast<const unsigned int*>(P + (size_t)row * 1536 + n);
    float v0 = bf2f((u16)(pv & 0xffffu)), v1 = bf2f((u16)(pv >> 16));
    float c = cosT[t * HD + d], s = sinT[t * HD + d];
    float o0 = (v0 * c - v1 * s) * scl;
    float o1 = (v1 * c + v0 * s) * scl;
    unsigned int ob = (unsigned int)f2bf(o0) | ((unsigned int)f2bf(o1) << 16);
    *reinterpret_cast<unsigned int*>(outp) = ob;
  } else {
    int rem = bid - 10240;
    int bh = rem >> 5, tt = rem & 31;
    int b = bh >> 2, kvh = bh & 3;
    int t0 = tt * 64;
    int colbase = 1024 + kvh * 128 + 64;
#pragma unroll
    for (int j = 0; j < 4; ++j) {
      int rr = j * 16 + (tid >> 4);
      int cc = (tid & 15) * 4;
      *reinterpret_cast<uint2*>(&tile[rr][cc]) =
          *reinterpret_cast<const uint2*>(P + (size_t)(b * Tt + t0 + rr) * 1536 + colbase + cc);
    }
    __syncthreads();
#pragma unroll
    for (int kk = 0; kk < 2; ++kk) {
      int CH = kk * 256 + tid;
      int df = CH >> 8, sbks = (CH >> 6) & 3, h8 = (CH >> 5) & 1, l = CH & 31;
      int d = df * 32 + l;
      int c = (sbks >> 1) * 4 + (sbks & 1) * 2 + h8;
      ushort8v v;
#pragma unroll
      for (int j = 0; j < 8; ++j) v[j] = tile[c * 8 + j][d];
      u16* dst = Vf + (size_t)bh * KVSZ + (((t0 >> 6) * 2 + df) * 4 + sbks) * 512 +
                 (h8 * 32 + l) * 8;
      *reinterpret_cast<ushort8v*>(dst) = v;
    }
  }
}

// ---------------------------------------------------------------- flash attention v11
// r11 structure (8 waves = {g}x{spl}, LDS-shared dbuf K/V via global_load_lds,
// static-max softmax, permlane pack, 2-way merge) with the step body
// half-tile PIPELINED to break phase-locked pipe bursts:
//   QK(h0) -> QK(h1) -> SM+pack(h0) -> PV(h0) -> SM+pack(h1) -> PV(h1)
// QK(h1) MFMAs interleave with SM(h0) VALU; PV(h0) with SM(h1).
__global__ __launch_bounds__(512, 4) void attn_fwd11(const u16* __restrict__ Q,
                                                     const u16* __restrict__ Kf,
                                                     const u16* __restrict__ Vf,
                                                     u16* __restrict__ Oa) {
  __shared__ alignas(16) u16 arena[32768];
  const int tid = threadIdx.x;
  const int w = tid >> 6, lane = tid & 63;
  const int g = w & 3, spl = w >> 2;
  const int l31 = lane & 31, hi = lane >> 5;

  const int fid = blockIdx.x;
  const int xcd = fid & 7, idx = fid >> 3;  // xcd == (b,kvh)
  const int b = xcd >> 2, kvh = xcd & 3;
  const int h = kvh * 4 + g;
  const int t0 = idx * 32;
  const size_t bh = (size_t)(b * KVH + kvh);

  // staging duty: rg = w&3 (0:K-s0 1:K-s1 2:V-s0 3:V-s1), half = spl
  const int rg = w & 3;
  const int sv = rg & 1, isV = rg >> 1;
  const u16* gsrc = (isV ? Vf : Kf) + bh * KVSZ + sv * 65536 + spl * 2048 + lane * 8;
  const int ldst0 = isV * 16384 + sv * 4096 + spl * 2048;

  const u16* Qh = Q + ((size_t)(b * QH + h) * Tt + t0 + l31) * HD + hi * 8;
  bf16x8 qf[4];
#pragma unroll
  for (int kf = 0; kf < 4; ++kf)
    qf[kf] = *reinterpret_cast<const bf16x8*>(Qh + kf * 16);

  f32x16 oacc[2];
#pragma unroll
  for (int df = 0; df < 2; ++df)
#pragma unroll
    for (int r = 0; r < 16; ++r) oacc[df][r] = 0.f;
  float lp = 0.f;

  // prologue: stage step 0 into buf 0
#pragma unroll
  for (int i = 0; i < 4; ++i) gld16(gsrc + i * 512, &arena[ldst0 + i * 512]);
  __syncthreads();

  int cur = 0;
  for (int it = 0; it < 16; ++it) {
    if (it < 15) {
      const u16* gs = gsrc + (it + 1) * 4096;
      u16* ld = &arena[ldst0 + (cur ^ 1) * 8192];
#pragma unroll
      for (int i = 0; i < 4; ++i) gld16(gs + i * 512, ld + i * 512);
    }
    const int ktb = cur * 8192 + spl * 4096;
    const int vtb = 16384 + cur * 8192 + spl * 4096;

    // ---- QK half 0 ----
    f32x16 s0;
    {
      bf16x8 k0[4];
#pragma unroll
      for (int kf = 0; kf < 4; ++kf)
        k0[kf] = *reinterpret_cast<const bf16x8*>(&arena[ktb + kf * 512 + lane * 8]);
#pragma unroll
      for (int r = 0; r < 16; ++r) s0[r] = 0.f;
      __builtin_amdgcn_s_setprio(1);
#pragma unroll
      for (int kf = 0; kf < 4; ++kf)
        s0 = __builtin_amdgcn_mfma_f32_32x32x16_bf16(k0[kf], qf[kf], s0, 0, 0, 0);
      __builtin_amdgcn_s_setprio(0);
    }
    // ---- QK half 1 (independent of SM(h0) below -> interleaves) ----
    f32x16 s1;
    {
      bf16x8 k1[4];
#pragma unroll
      for (int kf = 0; kf < 4; ++kf)
        k1[kf] = *reinterpret_cast<const bf16x8*>(&arena[ktb + 2048 + kf * 512 + lane * 8]);
#pragma unroll
      for (int r = 0; r < 16; ++r) s1[r] = 0.f;
      __builtin_amdgcn_s_setprio(1);
#pragma unroll
      for (int kf = 0; kf < 4; ++kf)
        s1 = __builtin_amdgcn_mfma_f32_32x32x16_bf16(k1[kf], qf[kf], s1, 0, 0, 0);
      __builtin_amdgcn_s_setprio(0);
    }

    // ---- SM + pack half 0 ----
    bf16x8 pf0[2];
    {
      float a0 = 0.f, a1 = 0.f, a2 = 0.f, a3 = 0.f;
#pragma unroll
      for (int r = 0; r < 16; r += 4) {
        float e0 = exp2r(s0[r]), e1 = exp2r(s0[r + 1]);
        float e2 = exp2r(s0[r + 2]), e3 = exp2r(s0[r + 3]);
        s0[r] = e0; s0[r + 1] = e1; s0[r + 2] = e2; s0[r + 3] = e3;
        a0 += e0; a1 += e1; a2 += e2; a3 += e3;
      }
      lp += (a0 + a1) + (a2 + a3);
      u32 pw[8];
#pragma unroll
      for (int r2 = 0; r2 < 8; ++r2) {
        u32 o;
        asm("v_cvt_pk_bf16_f32 %0, %1, %2" : "=v"(o) : "v"(s0[2 * r2]), "v"(s0[2 * r2 + 1]));
        pw[r2] = o;
      }
      u32 fw[2][4];
#pragma unroll
      for (int pp = 0; pp < 4; ++pp) {
        int ks = pp >> 1, o = pp & 1;
        u32 a = pw[ks * 4 + o], bq = pw[ks * 4 + o + 2];
        asm("v_permlane32_swap_b32 %0, %1" : "+v"(a), "+v"(bq));
        fw[ks][o] = a;
        fw[ks][o + 2] = bq;
      }
#pragma unroll
      for (int ks = 0; ks < 2; ++ks) {
        i32x4 iv = {(int)fw[ks][0], (int)fw[ks][1], (int)fw[ks][2], (int)fw[ks][3]};
        pf0[ks] = __builtin_bit_cast(bf16x8, iv);
      }
    }
    // ---- PV half 0 (independent of SM(h1) below -> interleaves) ----
    __builtin_amdgcn_s_setprio(1);
#pragma unroll
    for (int df = 0; df < 2; ++df)
#pragma unroll
      for (int ks = 0; ks < 2; ++ks) {
        bf16x8 vfr = *reinterpret_cast<const bf16x8*>(
            &arena[vtb + (df * 4 + ks) * 512 + lane * 8]);
        oacc[df] = __builtin_amdgcn_mfma_f32_32x32x16_bf16(vfr, pf0[ks], oacc[df], 0, 0, 0);
      }
    __builtin_amdgcn_s_setprio(0);

    // ---- SM + pack half 1 ----
    bf16x8 pf1[2];
    {
      float a0 = 0.f, a1 = 0.f, a2 = 0.f, a3 = 0.f;
#pragma unroll
      for (int r = 0; r < 16; r += 4) {
        float e0 = exp2r(s1[r]), e1 = exp2r(s1[r + 1]);
        float e2 = exp2r(s1[r + 2]), e3 = exp2r(s1[r + 3]);
        s1[r] = e0; s1[r + 1] = e1; s1[r + 2] = e2; s1[r + 3] = e3;
        a0 += e0; a1 += e1; a2 += e2; a3 += e3;
      }
      lp += (a0 + a1) + (a2 + a3);
      u32 pw[8];
#pragma unroll
      for (int r2 = 0; r2 < 8; ++r2) {
        u32 o;
        asm("v_cvt_pk_bf16_f32 %0, %1, %2" : "=v"(o) : "v"(s1[2 * r2]), "v"(s1[2 * r2 + 1]));
        pw[r2] = o;
      }
      u32 fw[2][4];
#pragma unroll
      for (int pp = 0; pp < 4; ++pp) {
        int ks = pp >> 1, o = pp & 1;
        u32 a = pw[ks * 4 + o], bq = pw[ks * 4 + o + 2];
        asm("v_permlane32_swap_b32 %0, %1" : "+v"(a), "+v"(bq));
        fw[ks][o] = a;
        fw[ks][o + 2] = bq;
      }
#pragma unroll
      for (int ks = 0; ks < 2; ++ks) {
        i32x4 iv = {(int)fw[ks][0], (int)fw[ks][1], (int)fw[ks][2], (int)fw[ks][3]};
        pf1[ks] = __builtin_bit_cast(bf16x8, iv);
      }
    }
    // ---- PV half 1 ----
    __builtin_amdgcn_s_setprio(1);
#pragma unroll
    for (int df = 0; df < 2; ++df)
#pragma unroll
      for (int ks = 0; ks < 2; ++ks) {
        bf16x8 vfr = *reinterpret_cast<const bf16x8*>(
            &arena[vtb + (df * 4 + 2 + ks) * 512 + lane * 8]);
        oacc[df] = __builtin_amdgcn_mfma_f32_32x32x16_bf16(vfr, pf1[ks], oacc[df], 0, 0, 0);
      }
    __builtin_amdgcn_s_setprio(0);

    __syncthreads();  // drains stage loads + protects buffer swap
    cur ^= 1;
  }

  // ---- split merge (2 ways): spl1 publishes, spl0 adds; then store ----
  lp += __shfl_xor(lp, 32);
  float* cb = reinterpret_cast<float*>(arena) + ((size_t)g * 32 + l31) * 66;
  if (spl == 1) {
#pragma unroll
    for (int df = 0; df < 2; ++df)
#pragma unroll
      for (int r = 0; r < 16; ++r) {
        int d = df * 32 + (r & 3) + 8 * (r >> 2) + 4 * hi;
        cb[d] = oacc[df][r];
      }
    if (hi == 0) cb[64] = lp;
  }
  __syncthreads();
  if (spl == 0) {
    lp += cb[64];
    float linv = 1.0f / lp;
    u16* otg = arena + 17408 + g * 2304;
#pragma unroll
    for (int df = 0; df < 2; ++df)
#pragma unroll
      for (int r = 0; r < 16; ++r) {
        int d = df * 32 + (r & 3) + 8 * (r >> 2) + 4 * hi;
        otg[l31 * 72 + d] = f2bf((oacc[df][r] + cb[d]) * linv);
      }
  }
  __syncthreads();
  if (spl == 0) {
    const u16* otg = arena + 17408 + g * 2304;
    int tr = lane >> 1, dblk = (lane & 1) * 32;
    u16* gdst = Oa + ((size_t)(b * Tt + t0 + tr)) * Dd + h * HD + dblk;
#pragma unroll
    for (int c = 0; c < 4; ++c) {
      ushort8v vv = *reinterpret_cast<const ushort8v*>(&otg[tr * 72 + dblk + c * 8]);
      *reinterpret_cast<ushort8v*>(gdst + c * 8) = vv;
    }
  }
}

// ---------------------------------------------------------------- launch
extern "C" void kernel_launch(void* const* d_in, const int* in_sizes, int n_in, void* d_out,
                              int out_size, void* d_ws, size_t ws_size, hipStream_t stream) {
  (void)in_sizes; (void)n_in; (void)out_size; (void)ws_size;
  const float* x = (const float*)d_in[0];
  const float* cosT = (const float*)d_in[1];
  const float* sinT = (const float*)d_in[2];
  const float* Wq = (const float*)d_in[3];
  const float* Wkv = (const float*)d_in[4];
  const float* Wo = (const float*)d_in[5];

  char* p = (char*)d_ws;
  u16* xb = (u16*)p;   p += (size_t)4096 * 1024 * 2;
  u16* wqkv = (u16*)p; p += (size_t)1536 * 1024 * 2;
  u16* wob = (u16*)p;  p += (size_t)1024 * 1024 * 2;
  u16* Pbuf = (u16*)p; p += (size_t)4096 * 1536 * 2;
  u16* Qb = (u16*)p;   p += (size_t)Bb * QH * Tt * HD * 2;
  u16* Kbuf = (u16*)p; p += (size_t)Bb * KVH * Tt * HD * 2;
  u16* Vfb = (u16*)p;  p += (size_t)Bb * KVH * HD * Tt * 2;
  u16* Ob = Pbuf;  // Pbuf dead after rope_vt

  cvt_all<<<6656, 256, 0, stream>>>(x, Wq, Wkv, Wo, xb, wqkv, wob);
  gemm_bt<false, 2><<<dim3(24, 32), 256, 0, stream>>>(xb, wqkv, Pbuf, 4096, 1536, 1024);
  rope_vt<<<10496, 256, 0, stream>>>(Pbuf, cosT, sinT, Qb, Kbuf, Vfb);
  attn_fwd11<<<512, 512, 0, stream>>>(Qb, Kbuf, Vfb, Ob);
  gemm_bt<true, 2><<<dim3(16, 32), 256, 0, stream>>>(Ob, wob, d_out, 4096, 1024, 1024);
}

// Round 13
// 98.758 us; speedup vs baseline: 1.8310x; 1.0037x over previous
//
#include <hip/hip_runtime.h>

// GQA attention fused pipeline for MI355X (gfx950).
// cvt(fused) -> GEMM(QKV; gld16 dbuf 2-phase, swizzled source) -> fused
// RoPE/scatter + V-transpose (fragment-major) -> flash attention (r11: LDS-
// shared K/V, static-max softmax) -> GEMM(out; same gld16 structure, BN=64).

typedef __bf16 bf16x8 __attribute__((ext_vector_type(8)));
typedef float f32x4 __attribute__((ext_vector_type(4)));
typedef float f32x16 __attribute__((ext_vector_type(16)));
typedef int i32x4 __attribute__((ext_vector_type(4)));
typedef unsigned short ushort4v __attribute__((ext_vector_type(4)));
typedef unsigned short ushort8v __attribute__((ext_vector_type(8)));
typedef unsigned short u16;
typedef unsigned int u32;

#define DEVINL __device__ __forceinline__

DEVINL float bf2f(u16 u) {
  unsigned int x = ((unsigned int)u) << 16;
  return __builtin_bit_cast(float, x);
}
DEVINL u16 f2bf(float f) {  // RTNE
  unsigned int x = __builtin_bit_cast(unsigned int, f);
  x += 0x7fffu + ((x >> 16) & 1u);
  return (u16)(x >> 16);
}
// raw 2^x — single v_exp_f32
DEVINL float exp2r(float x) {
  float r;
  asm("v_exp_f32 %0, %1" : "=v"(r) : "v"(x));
  return r;
}
// async global->LDS, 16B/lane; LDS dest = wave-uniform base + lane*16
DEVINL void gld16(const u16* g, u16* l) {
  __builtin_amdgcn_global_load_lds(
      (const __attribute__((address_space(1))) void*)g,
      (__attribute__((address_space(3))) void*)l, 16, 0, 0);
}

constexpr int Bb = 2, Tt = 2048, Dd = 1024, QH = 16, KVH = 4, HD = 64;
constexpr float SCALE_L2E = 0.125f * 1.44269504088896340736f;
constexpr int KVSZ = 131072;  // per-(b,kvh) fragment-major K/V extent (elems)

// ---------------------------------------------------------------- fused convert
__global__ void cvt_all(const float* __restrict__ x, const float* __restrict__ Wq,
                        const float* __restrict__ Wkv, const float* __restrict__ Wo,
                        u16* __restrict__ xb, u16* __restrict__ wqkv,
                        u16* __restrict__ wob) {
  int i = blockIdx.x * 256 + threadIdx.x;  // grid covers 1,703,936 float4s exactly
  const float* src;
  u16* dst;
  if (i < 1048576) {
    src = x; dst = xb;
  } else if (i < 1310720) {
    src = Wq - (size_t)1048576 * 4; dst = wqkv - (size_t)1048576 * 4;
  } else if (i < 1441792) {
    src = Wkv - (size_t)1310720 * 4; dst = wqkv + (size_t)1024 * 1024 - (size_t)1310720 * 4;
  } else {
    src = Wo - (size_t)1441792 * 4; dst = wob - (size_t)1441792 * 4;
  }
  float4 v = reinterpret_cast<const float4*>(src)[i];
  ushort4v o = {f2bf(v.x), f2bf(v.y), f2bf(v.z), f2bf(v.w)};
  *reinterpret_cast<ushort4v*>(dst + (size_t)i * 4) = o;
}

// ---------------------------------------------------------------- GEMM C = A(M,K) @ B(N,K)^T
// T3 2-phase with global_load_lds: double-buffered LDS; per K-step issue
// STAGE(next) BEFORE compute(cur) so the barrier's vmcnt(0) drain is covered
// by the MFMA phase. Global source pre-swizzled (csw = sc^(sr&7), rule #21)
// so linear gld16 dest yields conflict-free swizzled ds_read_b128 fragments.
// BM=128, BN=BNF*32 (BNF=2 -> 64 wide, grids 768/512 blocks = 3/2 per CU).
template <bool OUT_F32, int BNF>
__global__ __launch_bounds__(256) void gemm_bt(const u16* __restrict__ A,
                                               const u16* __restrict__ Bw,
                                               void* __restrict__ Cout, int M, int N, int K) {
  __shared__ alignas(16) u16 lA[2][128 * 64];
  __shared__ alignas(16) u16 lB[2][BNF * 32 * 64];
  const int tid = threadIdx.x;
  const int w = tid >> 6, lane = tid & 63;
  const int r16 = lane & 15, g4 = lane >> 4;
  const int row0 = blockIdx.y * 128, col0 = blockIdx.x * (BNF * 32);
  const int sr = tid >> 3, sc = tid & 7;
  const int csw = sc ^ (sr & 7);  // swizzled source chunk (involution per row)
  const int NT = K >> 6;
  const int wm = (w >> 1) * 64, wn2 = (w & 1) * (BNF * 16);

  f32x4 acc[4][BNF];
#pragma unroll
  for (int i = 0; i < 4; ++i)
#pragma unroll
    for (int j = 0; j < BNF; ++j) acc[i][j] = f32x4{0.f, 0.f, 0.f, 0.f};

  const u16* Abase = A + (size_t)(row0 + sr) * K + csw * 8;
  const u16* Bbase = Bw + (size_t)(col0 + sr) * K + csw * 8;

  auto stage = [&](int buf, int kt) {
    const int k0 = kt << 6;
#pragma unroll
    for (int i = 0; i < 4; ++i)
      gld16(Abase + (size_t)(i * 32) * K + k0, &lA[buf][i * 2048 + w * 512]);
#pragma unroll
    for (int i = 0; i < BNF; ++i)
      gld16(Bbase + (size_t)(i * 32) * K + k0, &lB[buf][i * 2048 + w * 512]);
  };

  // prologue: stage k-tile 0 into buf 0; barrier drains vmcnt
  stage(0, 0);
  __syncthreads();

  int cur = 0;
  for (int kt = 0; kt < NT; ++kt) {
    if (kt + 1 < NT) stage(cur ^ 1, kt + 1);  // in flight across compute below
#pragma unroll
    for (int kk = 0; kk < 2; ++kk) {
      bf16x8 af[4], bfr[BNF];
#pragma unroll
      for (int mf = 0; mf < 4; ++mf) {
        int r = wm + mf * 16 + r16;
        int c = (kk * 4 + g4) ^ (r & 7);
        af[mf] = *reinterpret_cast<const bf16x8*>(&lA[cur][r * 64 + c * 8]);
      }
#pragma unroll
      for (int nf = 0; nf < BNF; ++nf) {
        int r = wn2 + nf * 16 + r16;
        int c = (kk * 4 + g4) ^ (r & 7);
        bfr[nf] = *reinterpret_cast<const bf16x8*>(&lB[cur][r * 64 + c * 8]);
      }
#pragma unroll
      for (int mf = 0; mf < 4; ++mf)
#pragma unroll
        for (int nf = 0; nf < BNF; ++nf)
          acc[mf][nf] =
              __builtin_amdgcn_mfma_f32_16x16x32_bf16(af[mf], bfr[nf], acc[mf][nf], 0, 0, 0);
    }
    __syncthreads();  // drains next-tile stage (covered by MFMA) + WAR protect
    cur ^= 1;
  }

#pragma unroll
  for (int mf = 0; mf < 4; ++mf)
#pragma unroll
    for (int nf = 0; nf < BNF; ++nf)
#pragma unroll
      for (int r = 0; r < 4; ++r) {
        size_t row = (size_t)(row0 + wm + mf * 16 + g4 * 4 + r);
        size_t col = (size_t)(col0 + wn2 + nf * 16 + r16);
        float v = acc[mf][nf][r];
        if (OUT_F32)
          reinterpret_cast<float*>(Cout)[row * N + col] = v;
        else
          reinterpret_cast<u16*>(Cout)[row * N + col] = f2bf(v);
      }
}

// ---------------------------------------------------------------- fused RoPE/scatter + V-transpose
__global__ void rope_vt(const u16* __restrict__ P, const float* __restrict__ cosT,
                        const float* __restrict__ sinT, u16* __restrict__ Q,
                        u16* __restrict__ Kc, u16* __restrict__ Vf) {
  __shared__ u16 tile[64][72];
  const int bid = blockIdx.x;
  const int tid = threadIdx.x;
  if (bid < 10240) {
    int idx = bid * 256 + tid;
    int row = idx / 640, p = idx - row * 640;
    int b = row >> 11, t = row & 2047;
    int n, d;
    u16* outp;
    float scl;
    if (p < 512) {
      n = p * 2;
      int h = n >> 6;
      d = n & 63;
      outp = Q + ((size_t)(b * QH + h) * Tt + t) * HD + d;
      scl = SCALE_L2E;
    } else {
      int r2 = p - 512;
      int kvh = r2 >> 5, dp = r2 & 31;
      d = dp * 2;
      n = 1024 + kvh * 128 + d;
      int bh = b * KVH + kvh;
      int kf = d >> 4, h8 = (d >> 3) & 1, j = d & 7;  // j even
      outp = Kc + (size_t)bh * KVSZ + ((t >> 5) * 4 + kf) * 512 + (h8 * 32 + (t & 31)) * 8 + j;
      scl = 1.0f;
    }
    unsigned int pv = *reinterpret_cast<const unsigned int*>(P + (size_t)row * 1536 + n);
    float v0 = bf2f((u16)(pv & 0xffffu)), v1 = bf2f((u16)(pv >> 16));
    float c = cosT[t * HD + d], s = sinT[t * HD + d];
    float o0 = (v0 * c - v1 * s) * scl;
    float o1 = (v1 * c + v0 * s) * scl;
    unsigned int ob = (unsigned int)f2bf(o0) | ((unsigned int)f2bf(o1) << 16);
    *reinterpret_cast<unsigned int*>(outp) = ob;
  } else {
    int rem = bid - 10240;
    int bh = rem >> 5, tt = rem & 31;
    int b = bh >> 2, kvh = bh & 3;
    int t0 = tt * 64;
    int colbase = 1024 + kvh * 128 + 64;
#pragma unroll
    for (int j = 0; j < 4; ++j) {
      int rr = j * 16 + (tid >> 4);
      int cc = (tid & 15) * 4;
      *reinterpret_cast<uint2*>(&tile[rr][cc]) =
          *reinterpret_cast<const uint2*>(P + (size_t)(b * Tt + t0 + rr) * 1536 + colbase + cc);
    }
    __syncthreads();
#pragma unroll
    for (int kk = 0; kk < 2; ++kk) {
      int CH = kk * 256 + tid;
      int df = CH >> 8, sbks = (CH >> 6) & 3, h8 = (CH >> 5) & 1, l = CH & 31;
      int d = df * 32 + l;
      int c = (sbks >> 1) * 4 + (sbks & 1) * 2 + h8;
      ushort8v v;
#pragma unroll
      for (int j = 0; j < 8; ++j) v[j] = tile[c * 8 + j][d];
      u16* dst = Vf + (size_t)bh * KVSZ + (((t0 >> 6) * 2 + df) * 4 + sbks) * 512 +
                 (h8 * 32 + l) * 8;
      *reinterpret_cast<ushort8v*>(dst) = v;
    }
  }
}

// ---------------------------------------------------------------- flash attention (r11, proven 45.5us)
__global__ __launch_bounds__(512, 4) void attn_fwd10(const u16* __restrict__ Q,
                                                     const u16* __restrict__ Kf,
                                                     const u16* __restrict__ Vf,
                                                     u16* __restrict__ Oa) {
  __shared__ alignas(16) u16 arena[32768];
  const int tid = threadIdx.x;
  const int w = tid >> 6, lane = tid & 63;
  const int g = w & 3, spl = w >> 2;
  const int l31 = lane & 31, hi = lane >> 5;

  const int fid = blockIdx.x;
  const int xcd = fid & 7, idx = fid >> 3;  // xcd == (b,kvh)
  const int b = xcd >> 2, kvh = xcd & 3;
  const int h = kvh * 4 + g;
  const int t0 = idx * 32;
  const size_t bh = (size_t)(b * KVH + kvh);

  const int rg = w & 3;
  const int sv = rg & 1, isV = rg >> 1;
  const u16* gsrc = (isV ? Vf : Kf) + bh * KVSZ + sv * 65536 + spl * 2048 + lane * 8;
  const int ldst0 = isV * 16384 + sv * 4096 + spl * 2048;

  const u16* Qh = Q + ((size_t)(b * QH + h) * Tt + t0 + l31) * HD + hi * 8;
  bf16x8 qf[4];
#pragma unroll
  for (int kf = 0; kf < 4; ++kf)
    qf[kf] = *reinterpret_cast<const bf16x8*>(Qh + kf * 16);

  f32x16 oacc[2];
#pragma unroll
  for (int df = 0; df < 2; ++df)
#pragma unroll
    for (int r = 0; r < 16; ++r) oacc[df][r] = 0.f;
  float lp = 0.f;

#pragma unroll
  for (int i = 0; i < 4; ++i) gld16(gsrc + i * 512, &arena[ldst0 + i * 512]);
  __syncthreads();

  int cur = 0;
  for (int it = 0; it < 16; ++it) {
    if (it < 15) {
      const u16* gs = gsrc + (it + 1) * 4096;
      u16* ld = &arena[ldst0 + (cur ^ 1) * 8192];
#pragma unroll
      for (int i = 0; i < 4; ++i) gld16(gs + i * 512, ld + i * 512);
    }
    const int ktb = cur * 8192 + spl * 4096;
    const int vtb = 16384 + cur * 8192 + spl * 4096;

    // ---- QK^T from LDS fragments ----
    f32x16 sacc[2];
#pragma unroll
    for (int sb = 0; sb < 2; ++sb) {
      bf16x8 kfr[4];
#pragma unroll
      for (int kf = 0; kf < 4; ++kf)
        kfr[kf] = *reinterpret_cast<const bf16x8*>(&arena[ktb + sb * 2048 + kf * 512 + lane * 8]);
#pragma unroll
      for (int r = 0; r < 16; ++r) sacc[sb][r] = 0.f;
      __builtin_amdgcn_s_setprio(1);
#pragma unroll
      for (int kf = 0; kf < 4; ++kf)
        sacc[sb] = __builtin_amdgcn_mfma_f32_32x32x16_bf16(kfr[kf], qf[kf], sacc[sb], 0, 0, 0);
      __builtin_amdgcn_s_setprio(0);
    }

    // ---- static-max softmax: P = 2^s ----
    float a0 = 0.f, a1 = 0.f, a2 = 0.f, a3 = 0.f;
#pragma unroll
    for (int sb = 0; sb < 2; ++sb)
#pragma unroll
      for (int r = 0; r < 16; r += 4) {
        float e0 = exp2r(sacc[sb][r]);
        float e1 = exp2r(sacc[sb][r + 1]);
        float e2 = exp2r(sacc[sb][r + 2]);
        float e3 = exp2r(sacc[sb][r + 3]);
        sacc[sb][r] = e0; sacc[sb][r + 1] = e1; sacc[sb][r + 2] = e2; sacc[sb][r + 3] = e3;
        a0 += e0; a1 += e1; a2 += e2; a3 += e3;
      }
    lp += (a0 + a1) + (a2 + a3);

    // ---- pack P to B-frag layout via v_permlane32_swap_b32 ----
    bf16x8 pf[2][2];
#pragma unroll
    for (int sb = 0; sb < 2; ++sb) {
      u32 pw[8];
#pragma unroll
      for (int r2 = 0; r2 < 8; ++r2) {
        u32 o;
        asm("v_cvt_pk_bf16_f32 %0, %1, %2"
            : "=v"(o)
            : "v"(sacc[sb][2 * r2]), "v"(sacc[sb][2 * r2 + 1]));
        pw[r2] = o;
      }
      u32 fw[2][4];
#pragma unroll
      for (int pp = 0; pp < 4; ++pp) {
        int ks = pp >> 1, o = pp & 1;
        u32 a = pw[ks * 4 + o], bq = pw[ks * 4 + o + 2];
        asm("v_permlane32_swap_b32 %0, %1" : "+v"(a), "+v"(bq));
        fw[ks][o] = a;
        fw[ks][o + 2] = bq;
      }
#pragma unroll
      for (int ks = 0; ks < 2; ++ks) {
        i32x4 iv = {(int)fw[ks][0], (int)fw[ks][1], (int)fw[ks][2], (int)fw[ks][3]};
        pf[sb][ks] = __builtin_bit_cast(bf16x8, iv);
      }
    }

    // ---- PV from LDS V fragments ----
    __builtin_amdgcn_s_setprio(1);
#pragma unroll
    for (int df = 0; df < 2; ++df)
#pragma unroll
      for (int sb = 0; sb < 2; ++sb)
#pragma unroll
        for (int ks = 0; ks < 2; ++ks) {
          bf16x8 vfr = *reinterpret_cast<const bf16x8*>(
              &arena[vtb + (df * 4 + sb * 2 + ks) * 512 + lane * 8]);
          oacc[df] = __builtin_amdgcn_mfma_f32_32x32x16_bf16(vfr, pf[sb][ks], oacc[df], 0, 0, 0);
        }
    __builtin_amdgcn_s_setprio(0);

    __syncthreads();
    cur ^= 1;
  }

  // ---- split merge (2 ways) + store ----
  lp += __shfl_xor(lp, 32);
  float* cb = reinterpret_cast<float*>(arena) + ((size_t)g * 32 + l31) * 66;
  if (spl == 1) {
#pragma unroll
    for (int df = 0; df < 2; ++df)
#pragma unroll
      for (int r = 0; r < 16; ++r) {
        int d = df * 32 + (r & 3) + 8 * (r >> 2) + 4 * hi;
        cb[d] = oacc[df][r];
      }
    if (hi == 0) cb[64] = lp;
  }
  __syncthreads();
  if (spl == 0) {
    lp += cb[64];
    float linv = 1.0f / lp;
    u16* otg = arena + 17408 + g * 2304;
#pragma unroll
    for (int df = 0; df < 2; ++df)
#pragma unroll
      for (int r = 0; r < 16; ++r) {
        int d = df * 32 + (r & 3) + 8 * (r >> 2) + 4 * hi;
        otg[l31 * 72 + d] = f2bf((oacc[df][r] + cb[d]) * linv);
      }
  }
  __syncthreads();
  if (spl == 0) {
    const u16* otg = arena + 17408 + g * 2304;
    int tr = lane >> 1, dblk = (lane & 1) * 32;
    u16* gdst = Oa + ((size_t)(b * Tt + t0 + tr)) * Dd + h * HD + dblk;
#pragma unroll
    for (int c = 0; c < 4; ++c) {
      ushort8v vv = *reinterpret_cast<const ushort8v*>(&otg[tr * 72 + dblk + c * 8]);
      *reinterpret_cast<ushort8v*>(gdst + c * 8) = vv;
    }
  }
}

// ---------------------------------------------------------------- launch
extern "C" void kernel_launch(void* const* d_in, const int* in_sizes, int n_in, void* d_out,
                              int out_size, void* d_ws, size_t ws_size, hipStream_t stream) {
  (void)in_sizes; (void)n_in; (void)out_size; (void)ws_size;
  const float* x = (const float*)d_in[0];
  const float* cosT = (const float*)d_in[1];
  const float* sinT = (const float*)d_in[2];
  const float* Wq = (const float*)d_in[3];
  const float* Wkv = (const float*)d_in[4];
  const float* Wo = (const float*)d_in[5];

  char* p = (char*)d_ws;
  u16* xb = (u16*)p;   p += (size_t)4096 * 1024 * 2;
  u16* wqkv = (u16*)p; p += (size_t)1536 * 1024 * 2;
  u16* wob = (u16*)p;  p += (size_t)1024 * 1024 * 2;
  u16* Pbuf = (u16*)p; p += (size_t)4096 * 1536 * 2;
  u16* Qb = (u16*)p;   p += (size_t)Bb * QH * Tt * HD * 2;
  u16* Kbuf = (u16*)p; p += (size_t)Bb * KVH * Tt * HD * 2;
  u16* Vfb = (u16*)p;  p += (size_t)Bb * KVH * HD * Tt * 2;
  u16* Ob = Pbuf;  // Pbuf dead after rope_vt

  cvt_all<<<6656, 256, 0, stream>>>(x, Wq, Wkv, Wo, xb, wqkv, wob);
  gemm_bt<false, 2><<<dim3(24, 32), 256, 0, stream>>>(xb, wqkv, Pbuf, 4096, 1536, 1024);
  rope_vt<<<10496, 256, 0, stream>>>(Pbuf, cosT, sinT, Qb, Kbuf, Vfb);
  attn_fwd10<<<512, 512, 0, stream>>>(Qb, Kbuf, Vfb, Ob);
  gemm_bt<true, 2><<<dim3(16, 32), 256, 0, stream>>>(Ob, wob, d_out, 4096, 1024, 1024);
}

// Round 14
// 92.910 us; speedup vs baseline: 1.9462x; 1.0630x over previous
//
#include <hip/hip_runtime.h>

// GQA attention fused pipeline for MI355X (gfx950).
// cvt(fused) -> GEMM-QKV with FUSED RoPE/scatter/V-transpose epilogue
// (writes Q row-major + K,V fragment-major directly from accumulators)
// -> flash attention (LDS-shared K/V, static-max softmax) -> GEMM(out, BN=64).

typedef __bf16 bf16x8 __attribute__((ext_vector_type(8)));
typedef float f32x4 __attribute__((ext_vector_type(4)));
typedef float f32x16 __attribute__((ext_vector_type(16)));
typedef int i32x4 __attribute__((ext_vector_type(4)));
typedef unsigned short ushort4v __attribute__((ext_vector_type(4)));
typedef unsigned short ushort8v __attribute__((ext_vector_type(8)));
typedef unsigned short u16;
typedef unsigned int u32;

#define DEVINL __device__ __forceinline__

DEVINL float bf2f(u16 u) {
  unsigned int x = ((unsigned int)u) << 16;
  return __builtin_bit_cast(float, x);
}
DEVINL u16 f2bf(float f) {  // RTNE
  unsigned int x = __builtin_bit_cast(unsigned int, f);
  x += 0x7fffu + ((x >> 16) & 1u);
  return (u16)(x >> 16);
}
// raw 2^x — single v_exp_f32
DEVINL float exp2r(float x) {
  float r;
  asm("v_exp_f32 %0, %1" : "=v"(r) : "v"(x));
  return r;
}
// async global->LDS, 16B/lane; LDS dest = wave-uniform base + lane*16
DEVINL void gld16(const u16* g, u16* l) {
  __builtin_amdgcn_global_load_lds(
      (const __attribute__((address_space(1))) void*)g,
      (__attribute__((address_space(3))) void*)l, 16, 0, 0);
}

constexpr int Bb = 2, Tt = 2048, Dd = 1024, QH = 16, KVH = 4, HD = 64;
constexpr float SCALE_L2E = 0.125f * 1.44269504088896340736f;
constexpr int KVSZ = 131072;  // per-(b,kvh) fragment-major K/V extent (elems)

// ---------------------------------------------------------------- fused convert
__global__ void cvt_all(const float* __restrict__ x, const float* __restrict__ Wq,
                        const float* __restrict__ Wkv, const float* __restrict__ Wo,
                        u16* __restrict__ xb, u16* __restrict__ wqkv,
                        u16* __restrict__ wob) {
  int i = blockIdx.x * 256 + threadIdx.x;  // grid covers 1,703,936 float4s exactly
  const float* src;
  u16* dst;
  if (i < 1048576) {
    src = x; dst = xb;
  } else if (i < 1310720) {
    src = Wq - (size_t)1048576 * 4; dst = wqkv - (size_t)1048576 * 4;
  } else if (i < 1441792) {
    src = Wkv - (size_t)1310720 * 4; dst = wqkv + (size_t)1024 * 1024 - (size_t)1310720 * 4;
  } else {
    src = Wo - (size_t)1441792 * 4; dst = wob - (size_t)1441792 * 4;
  }
  float4 v = reinterpret_cast<const float4*>(src)[i];
  ushort4v o = {f2bf(v.x), f2bf(v.y), f2bf(v.z), f2bf(v.w)};
  *reinterpret_cast<ushort4v*>(dst + (size_t)i * 4) = o;
}

// ---------------------------------------------------------------- GEMM main-loop macro body
// reg-staged prefetch; BM=128, BN=64 (BNF=2). 4 waves, XOR-swizzled LDS chunks.
// Shared by gemm_qkv (fused rope epilogue) and gemm_bt (plain epilogue).

// ---------------------------------------------------------------- QKV GEMM + fused RoPE/scatter
// C = xb(4096,1024) @ wqkv(1536,1024)^T. Each block's 64-col range is entirely
// one q-head / k-half / v-half. Epilogue applies RoPE in f32 via shfl_xor(1)
// (pair (d,d+1) = adjacent lanes) and writes Q row-major (pre-scaled),
// K & V fragment-major — Pbuf round-trip and rope_vt kernel eliminated.
__global__ __launch_bounds__(256) void gemm_qkv(const u16* __restrict__ A,
                                                const u16* __restrict__ Bw,
                                                const float* __restrict__ cosT,
                                                const float* __restrict__ sinT,
                                                u16* __restrict__ Qb,
                                                u16* __restrict__ Kf,
                                                u16* __restrict__ Vf) {
  constexpr int K = 1024;
  __shared__ alignas(16) u16 lA[128 * 64];
  __shared__ alignas(16) u16 lB[64 * 64];
  const int tid = threadIdx.x;
  const int w = tid >> 6, lane = tid & 63;
  const int r16 = lane & 15, g4 = lane >> 4;
  const int row0 = blockIdx.y * 128, col0 = blockIdx.x * 64;
  const int sr = tid >> 3, sc = tid & 7;
  const int NT = K >> 6;

  bf16x8 ra[4], rb[2];
  f32x4 acc[4][2];
#pragma unroll
  for (int i = 0; i < 4; ++i)
#pragma unroll
    for (int j = 0; j < 2; ++j) acc[i][j] = f32x4{0.f, 0.f, 0.f, 0.f};

  const int wm = (w >> 1) * 64, wn2 = (w & 1) * 32;

#pragma unroll
  for (int i = 0; i < 4; ++i) {
    int r = i * 32 + sr;
    ra[i] = *reinterpret_cast<const bf16x8*>(A + (size_t)(row0 + r) * K + sc * 8);
  }
#pragma unroll
  for (int i = 0; i < 2; ++i) {
    int r = i * 32 + sr;
    rb[i] = *reinterpret_cast<const bf16x8*>(Bw + (size_t)(col0 + r) * K + sc * 8);
  }

  for (int kt = 0; kt < NT; ++kt) {
    __syncthreads();
#pragma unroll
    for (int i = 0; i < 4; ++i) {
      int r = i * 32 + sr;
      int c = (sc ^ (r & 7)) * 8;
      *reinterpret_cast<bf16x8*>(&lA[r * 64 + c]) = ra[i];
    }
#pragma unroll
    for (int i = 0; i < 2; ++i) {
      int r = i * 32 + sr;
      int c = (sc ^ (r & 7)) * 8;
      *reinterpret_cast<bf16x8*>(&lB[r * 64 + c]) = rb[i];
    }
    __syncthreads();
    if (kt + 1 < NT) {
      int k0 = (kt + 1) << 6;
#pragma unroll
      for (int i = 0; i < 4; ++i) {
        int r = i * 32 + sr;
        ra[i] = *reinterpret_cast<const bf16x8*>(A + (size_t)(row0 + r) * K + k0 + sc * 8);
      }
#pragma unroll
      for (int i = 0; i < 2; ++i) {
        int r = i * 32 + sr;
        rb[i] = *reinterpret_cast<const bf16x8*>(Bw + (size_t)(col0 + r) * K + k0 + sc * 8);
      }
    }
#pragma unroll
    for (int kk = 0; kk < 2; ++kk) {
      bf16x8 af[4], bfr[2];
#pragma unroll
      for (int mf = 0; mf < 4; ++mf) {
        int r = wm + mf * 16 + r16;
        int c = ((kk * 4 + g4) ^ (r & 7)) * 8;
        af[mf] = *reinterpret_cast<const bf16x8*>(&lA[r * 64 + c]);
      }
#pragma unroll
      for (int nf = 0; nf < 2; ++nf) {
        int r = wn2 + nf * 16 + r16;
        int c = ((kk * 4 + g4) ^ (r & 7)) * 8;
        bfr[nf] = *reinterpret_cast<const bf16x8*>(&lB[r * 64 + c]);
      }
#pragma unroll
      for (int mf = 0; mf < 4; ++mf)
#pragma unroll
        for (int nf = 0; nf < 2; ++nf)
          acc[mf][nf] =
              __builtin_amdgcn_mfma_f32_16x16x32_bf16(af[mf], bfr[nf], acc[mf][nf], 0, 0, 0);
    }
  }

  // ---- fused epilogue: rope + scatter straight from f32 accumulators ----
  // pair partner (d xor 1) is the adjacent lane (d parity == r16 parity)
  const float psign = (r16 & 1) ? 1.f : -1.f;
  if (col0 < 1024) {  // ---- Q head: rope, pre-scale, row-major ----
    const int hq = col0 >> 6;
#pragma unroll
    for (int nf = 0; nf < 2; ++nf) {
      const int d = wn2 + nf * 16 + r16;
#pragma unroll
      for (int mf = 0; mf < 4; ++mf)
#pragma unroll
        for (int r = 0; r < 4; ++r) {
          int bt = row0 + wm + mf * 16 + g4 * 4 + r;
          int b = bt >> 11, t = bt & 2047;
          float v = acc[mf][nf][r];
          float pv = __shfl_xor(v, 1);
          float c = cosT[t * 64 + d] * SCALE_L2E;
          float s = sinT[t * 64 + d] * SCALE_L2E;
          float o = v * c + psign * pv * s;
          Qb[((size_t)(b * QH + hq) * Tt + t) * HD + d] = f2bf(o);
        }
    }
  } else {
    const int kvcol = col0 - 1024;
    const int kvh = kvcol >> 7, isv = (kvcol >> 6) & 1;
    if (!isv) {  // ---- K: rope (unscaled), fragment-major ----
#pragma unroll
      for (int nf = 0; nf < 2; ++nf) {
        const int d = wn2 + nf * 16 + r16;
        const int kf = d >> 4, h8 = (d >> 3) & 1, j = d & 7;
#pragma unroll
        for (int mf = 0; mf < 4; ++mf)
#pragma unroll
          for (int r = 0; r < 4; ++r) {
            int bt = row0 + wm + mf * 16 + g4 * 4 + r;
            int b = bt >> 11, t = bt & 2047;
            float v = acc[mf][nf][r];
            float pv = __shfl_xor(v, 1);
            float c = cosT[t * 64 + d], s = sinT[t * 64 + d];
            float o = v * c + psign * pv * s;
            size_t bh = (size_t)(b * KVH + kvh);
            Kf[bh * KVSZ + ((t >> 5) * 4 + kf) * 512 + (h8 * 32 + (t & 31)) * 8 + j] = f2bf(o);
          }
      }
    } else {  // ---- V: straight cast, fragment-major transpose ----
#pragma unroll
      for (int nf = 0; nf < 2; ++nf) {
        const int d = wn2 + nf * 16 + r16;
        const int df = d >> 5, l = d & 31;
#pragma unroll
        for (int mf = 0; mf < 4; ++mf)
#pragma unroll
          for (int r = 0; r < 4; ++r) {
            int bt = row0 + wm + mf * 16 + g4 * 4 + r;
            int b = bt >> 11, t = bt & 2047;
            size_t bh = (size_t)(b * KVH + kvh);
            size_t addr = bh * KVSZ +
                          (((t >> 6) * 2 + df) * 4 + ((t >> 4) & 3)) * 512 +
                          (((t >> 3) & 1) * 32 + l) * 8 + (t & 7);
            Vf[addr] = f2bf(acc[mf][nf][r]);
          }
      }
    }
  }
}

// ---------------------------------------------------------------- plain GEMM (out-proj)
template <bool OUT_F32, int BNF>
__global__ __launch_bounds__(256) void gemm_bt(const u16* __restrict__ A,
                                               const u16* __restrict__ Bw,
                                               void* __restrict__ Cout, int M, int N, int K) {
  __shared__ alignas(16) u16 lA[128 * 64];
  __shared__ alignas(16) u16 lB[BNF * 32 * 64];
  const int tid = threadIdx.x;
  const int w = tid >> 6, lane = tid & 63;
  const int r16 = lane & 15, g4 = lane >> 4;
  const int row0 = blockIdx.y * 128, col0 = blockIdx.x * (BNF * 32);
  const int sr = tid >> 3, sc = tid & 7;
  const int NT = K >> 6;

  bf16x8 ra[4], rb[BNF];
  f32x4 acc[4][BNF];
#pragma unroll
  for (int i = 0; i < 4; ++i)
#pragma unroll
    for (int j = 0; j < BNF; ++j) acc[i][j] = f32x4{0.f, 0.f, 0.f, 0.f};

  const int wm = (w >> 1) * 64, wn2 = (w & 1) * (BNF * 16);

#pragma unroll
  for (int i = 0; i < 4; ++i) {
    int r = i * 32 + sr;
    ra[i] = *reinterpret_cast<const bf16x8*>(A + (size_t)(row0 + r) * K + sc * 8);
  }
#pragma unroll
  for (int i = 0; i < BNF; ++i) {
    int r = i * 32 + sr;
    rb[i] = *reinterpret_cast<const bf16x8*>(Bw + (size_t)(col0 + r) * K + sc * 8);
  }

  for (int kt = 0; kt < NT; ++kt) {
    __syncthreads();
#pragma unroll
    for (int i = 0; i < 4; ++i) {
      int r = i * 32 + sr;
      int c = (sc ^ (r & 7)) * 8;
      *reinterpret_cast<bf16x8*>(&lA[r * 64 + c]) = ra[i];
    }
#pragma unroll
    for (int i = 0; i < BNF; ++i) {
      int r = i * 32 + sr;
      int c = (sc ^ (r & 7)) * 8;
      *reinterpret_cast<bf16x8*>(&lB[r * 64 + c]) = rb[i];
    }
    __syncthreads();
    if (kt + 1 < NT) {
      int k0 = (kt + 1) << 6;
#pragma unroll
      for (int i = 0; i < 4; ++i) {
        int r = i * 32 + sr;
        ra[i] = *reinterpret_cast<const bf16x8*>(A + (size_t)(row0 + r) * K + k0 + sc * 8);
      }
#pragma unroll
      for (int i = 0; i < BNF; ++i) {
        int r = i * 32 + sr;
        rb[i] = *reinterpret_cast<const bf16x8*>(Bw + (size_t)(col0 + r) * K + k0 + sc * 8);
      }
    }
#pragma unroll
    for (int kk = 0; kk < 2; ++kk) {
      bf16x8 af[4], bfr[BNF];
#pragma unroll
      for (int mf = 0; mf < 4; ++mf) {
        int r = wm + mf * 16 + r16;
        int c = ((kk * 4 + g4) ^ (r & 7)) * 8;
        af[mf] = *reinterpret_cast<const bf16x8*>(&lA[r * 64 + c]);
      }
#pragma unroll
      for (int nf = 0; nf < BNF; ++nf) {
        int r = wn2 + nf * 16 + r16;
        int c = ((kk * 4 + g4) ^ (r & 7)) * 8;
        bfr[nf] = *reinterpret_cast<const bf16x8*>(&lB[r * 64 + c]);
      }
#pragma unroll
      for (int mf = 0; mf < 4; ++mf)
#pragma unroll
        for (int nf = 0; nf < BNF; ++nf)
          acc[mf][nf] =
              __builtin_amdgcn_mfma_f32_16x16x32_bf16(af[mf], bfr[nf], acc[mf][nf], 0, 0, 0);
    }
  }

#pragma unroll
  for (int mf = 0; mf < 4; ++mf)
#pragma unroll
    for (int nf = 0; nf < BNF; ++nf)
#pragma unroll
      for (int r = 0; r < 4; ++r) {
        size_t row = (size_t)(row0 + wm + mf * 16 + g4 * 4 + r);
        size_t col = (size_t)(col0 + wn2 + nf * 16 + r16);
        float v = acc[mf][nf][r];
        if (OUT_F32)
          reinterpret_cast<float*>(Cout)[row * N + col] = v;
        else
          reinterpret_cast<u16*>(Cout)[row * N + col] = f2bf(v);
      }
}

// ---------------------------------------------------------------- flash attention (r11, proven)
__global__ __launch_bounds__(512, 4) void attn_fwd10(const u16* __restrict__ Q,
                                                     const u16* __restrict__ Kf,
                                                     const u16* __restrict__ Vf,
                                                     u16* __restrict__ Oa) {
  __shared__ alignas(16) u16 arena[32768];
  const int tid = threadIdx.x;
  const int w = tid >> 6, lane = tid & 63;
  const int g = w & 3, spl = w >> 2;
  const int l31 = lane & 31, hi = lane >> 5;

  const int fid = blockIdx.x;
  const int xcd = fid & 7, idx = fid >> 3;  // xcd == (b,kvh)
  const int b = xcd >> 2, kvh = xcd & 3;
  const int h = kvh * 4 + g;
  const int t0 = idx * 32;
  const size_t bh = (size_t)(b * KVH + kvh);

  const int rg = w & 3;
  const int sv = rg & 1, isV = rg >> 1;
  const u16* gsrc = (isV ? Vf : Kf) + bh * KVSZ + sv * 65536 + spl * 2048 + lane * 8;
  const int ldst0 = isV * 16384 + sv * 4096 + spl * 2048;

  const u16* Qh = Q + ((size_t)(b * QH + h) * Tt + t0 + l31) * HD + hi * 8;
  bf16x8 qf[4];
#pragma unroll
  for (int kf = 0; kf < 4; ++kf)
    qf[kf] = *reinterpret_cast<const bf16x8*>(Qh + kf * 16);

  f32x16 oacc[2];
#pragma unroll
  for (int df = 0; df < 2; ++df)
#pragma unroll
    for (int r = 0; r < 16; ++r) oacc[df][r] = 0.f;
  float lp = 0.f;

#pragma unroll
  for (int i = 0; i < 4; ++i) gld16(gsrc + i * 512, &arena[ldst0 + i * 512]);
  __syncthreads();

  int cur = 0;
  for (int it = 0; it < 16; ++it) {
    if (it < 15) {
      const u16* gs = gsrc + (it + 1) * 4096;
      u16* ld = &arena[ldst0 + (cur ^ 1) * 8192];
#pragma unroll
      for (int i = 0; i < 4; ++i) gld16(gs + i * 512, ld + i * 512);
    }
    const int ktb = cur * 8192 + spl * 4096;
    const int vtb = 16384 + cur * 8192 + spl * 4096;

    f32x16 sacc[2];
#pragma unroll
    for (int sb = 0; sb < 2; ++sb) {
      bf16x8 kfr[4];
#pragma unroll
      for (int kf = 0; kf < 4; ++kf)
        kfr[kf] = *reinterpret_cast<const bf16x8*>(&arena[ktb + sb * 2048 + kf * 512 + lane * 8]);
#pragma unroll
      for (int r = 0; r < 16; ++r) sacc[sb][r] = 0.f;
      __builtin_amdgcn_s_setprio(1);
#pragma unroll
      for (int kf = 0; kf < 4; ++kf)
        sacc[sb] = __builtin_amdgcn_mfma_f32_32x32x16_bf16(kfr[kf], qf[kf], sacc[sb], 0, 0, 0);
      __builtin_amdgcn_s_setprio(0);
    }

    float a0 = 0.f, a1 = 0.f, a2 = 0.f, a3 = 0.f;
#pragma unroll
    for (int sb = 0; sb < 2; ++sb)
#pragma unroll
      for (int r = 0; r < 16; r += 4) {
        float e0 = exp2r(sacc[sb][r]);
        float e1 = exp2r(sacc[sb][r + 1]);
        float e2 = exp2r(sacc[sb][r + 2]);
        float e3 = exp2r(sacc[sb][r + 3]);
        sacc[sb][r] = e0; sacc[sb][r + 1] = e1; sacc[sb][r + 2] = e2; sacc[sb][r + 3] = e3;
        a0 += e0; a1 += e1; a2 += e2; a3 += e3;
      }
    lp += (a0 + a1) + (a2 + a3);

    bf16x8 pf[2][2];
#pragma unroll
    for (int sb = 0; sb < 2; ++sb) {
      u32 pw[8];
#pragma unroll
      for (int r2 = 0; r2 < 8; ++r2) {
        u32 o;
        asm("v_cvt_pk_bf16_f32 %0, %1, %2"
            : "=v"(o)
            : "v"(sacc[sb][2 * r2]), "v"(sacc[sb][2 * r2 + 1]));
        pw[r2] = o;
      }
      u32 fw[2][4];
#pragma unroll
      for (int pp = 0; pp < 4; ++pp) {
        int ks = pp >> 1, o = pp & 1;
        u32 a = pw[ks * 4 + o], bq = pw[ks * 4 + o + 2];
        asm("v_permlane32_swap_b32 %0, %1" : "+v"(a), "+v"(bq));
        fw[ks][o] = a;
        fw[ks][o + 2] = bq;
      }
#pragma unroll
      for (int ks = 0; ks < 2; ++ks) {
        i32x4 iv = {(int)fw[ks][0], (int)fw[ks][1], (int)fw[ks][2], (int)fw[ks][3]};
        pf[sb][ks] = __builtin_bit_cast(bf16x8, iv);
      }
    }

    __builtin_amdgcn_s_setprio(1);
#pragma unroll
    for (int df = 0; df < 2; ++df)
#pragma unroll
      for (int sb = 0; sb < 2; ++sb)
#pragma unroll
        for (int ks = 0; ks < 2; ++ks) {
          bf16x8 vfr = *reinterpret_cast<const bf16x8*>(
              &arena[vtb + (df * 4 + sb * 2 + ks) * 512 + lane * 8]);
          oacc[df] = __builtin_amdgcn_mfma_f32_32x32x16_bf16(vfr, pf[sb][ks], oacc[df], 0, 0, 0);
        }
    __builtin_amdgcn_s_setprio(0);

    __syncthreads();
    cur ^= 1;
  }

  lp += __shfl_xor(lp, 32);
  float* cb = reinterpret_cast<float*>(arena) + ((size_t)g * 32 + l31) * 66;
  if (spl == 1) {
#pragma unroll
    for (int df = 0; df < 2; ++df)
#pragma unroll
      for (int r = 0; r < 16; ++r) {
        int d = df * 32 + (r & 3) + 8 * (r >> 2) + 4 * hi;
        cb[d] = oacc[df][r];
      }
    if (hi == 0) cb[64] = lp;
  }
  __syncthreads();
  if (spl == 0) {
    lp += cb[64];
    float linv = 1.0f / lp;
    u16* otg = arena + 17408 + g * 2304;
#pragma unroll
    for (int df = 0; df < 2; ++df)
#pragma unroll
      for (int r = 0; r < 16; ++r) {
        int d = df * 32 + (r & 3) + 8 * (r >> 2) + 4 * hi;
        otg[l31 * 72 + d] = f2bf((oacc[df][r] + cb[d]) * linv);
      }
  }
  __syncthreads();
  if (spl == 0) {
    const u16* otg = arena + 17408 + g * 2304;
    int tr = lane >> 1, dblk = (lane & 1) * 32;
    u16* gdst = Oa + ((size_t)(b * Tt + t0 + tr)) * Dd + h * HD + dblk;
#pragma unroll
    for (int c = 0; c < 4; ++c) {
      ushort8v vv = *reinterpret_cast<const ushort8v*>(&otg[tr * 72 + dblk + c * 8]);
      *reinterpret_cast<ushort8v*>(gdst + c * 8) = vv;
    }
  }
}

// ---------------------------------------------------------------- launch
extern "C" void kernel_launch(void* const* d_in, const int* in_sizes, int n_in, void* d_out,
                              int out_size, void* d_ws, size_t ws_size, hipStream_t stream) {
  (void)in_sizes; (void)n_in; (void)out_size; (void)ws_size;
  const float* x = (const float*)d_in[0];
  const float* cosT = (const float*)d_in[1];
  const float* sinT = (const float*)d_in[2];
  const float* Wq = (const float*)d_in[3];
  const float* Wkv = (const float*)d_in[4];
  const float* Wo = (const float*)d_in[5];

  char* p = (char*)d_ws;
  u16* xb = (u16*)p;   p += (size_t)4096 * 1024 * 2;
  u16* wqkv = (u16*)p; p += (size_t)1536 * 1024 * 2;
  u16* wob = (u16*)p;  p += (size_t)1024 * 1024 * 2;
  u16* Pbuf = (u16*)p; p += (size_t)4096 * 1536 * 2;
  u16* Qb = (u16*)p;   p += (size_t)Bb * QH * Tt * HD * 2;
  u16* Kbuf = (u16*)p; p += (size_t)Bb * KVH * Tt * HD * 2;
  u16* Vfb = (u16*)p;  p += (size_t)Bb * KVH * HD * Tt * 2;
  u16* Ob = Pbuf;  // attention-output staging (bf16), feeds gemm2

  cvt_all<<<6656, 256, 0, stream>>>(x, Wq, Wkv, Wo, xb, wqkv, wob);
  gemm_qkv<<<dim3(24, 32), 256, 0, stream>>>(xb, wqkv, cosT, sinT, Qb, Kbuf, Vfb);
  attn_fwd10<<<512, 512, 0, stream>>>(Qb, Kbuf, Vfb, Ob);
  gemm_bt<true, 2><<<dim3(16, 32), 256, 0, stream>>>(Ob, wob, d_out, 4096, 1024, 1024);
}